// Round 10
// baseline (227.363 us; speedup 1.0000x reference)
//
#include <hip/hip_runtime.h>
#include <math.h>

#define NN 50000
#define NE 800000
#define KD 256
#define OD 64
#define NCH ((NN + 255) / 256)   // 196 buckets/chunks of 256 nodes
#define EPB 4096                 // edges per histogram/bucket block
#define NBLK ((NE + EPB - 1) / EPB)   // 196 blocks
#define NHT (NCH * NBLK)         // histogram matrix entries (bin-major)

#define QS 32.0f      // int8 quant scale (fixed, power of 2)
#define IQS (1.0f / 32.0f)

using bf16x8 = __attribute__((ext_vector_type(8))) short;
using f32x4  = __attribute__((ext_vector_type(4))) float;

__device__ __forceinline__ unsigned short f2b(float x) {
    union { float f; unsigned u; } c; c.f = x;
    unsigned r = (c.u + 0x7FFF + ((c.u >> 16) & 1)) >> 16;
    return (unsigned short)r;
}
__device__ __forceinline__ float b2f(unsigned short b) {
    union { unsigned u; float f; } c; c.u = ((unsigned)b) << 16;
    return c.f;
}
__device__ __forceinline__ signed char quant8(float v) {
    int q = __float2int_rn(v * QS);
    q = q > 127 ? 127 : (q < -127 ? -127 : q);
    return (signed char)q;
}

// ---------------- CSR build (counting-sort, padded-to-8 segments) ----------------

// pass A: per-block bucket histogram (LDS atomics) + global per-node degree
__global__ __launch_bounds__(256) void k_hist(const int* __restrict__ dst,
                                              int* __restrict__ histT,
                                              int* __restrict__ deg) {
    __shared__ int bins[NCH];
    int t = threadIdx.x, blk = blockIdx.x;
    if (t < NCH) bins[t] = 0;
    __syncthreads();
    int base = blk * EPB;
    #pragma unroll
    for (int i = 0; i < EPB / 256; ++i) {
        int e = base + i * 256 + t;
        if (e < NE) {
            int d = dst[e];
            atomicAdd(&bins[d >> 8], 1);
            atomicAdd(&deg[d], 1);
        }
    }
    __syncthreads();
    if (t < NCH) histT[t * NBLK + blk] = bins[t];   // bin-major
}

// per-chunk sum of PADDED degrees
__global__ void k_chunk_sum8(const int* __restrict__ deg, int* __restrict__ chunkSum8) {
    __shared__ int s[256];
    int g = blockIdx.x * 256 + threadIdx.x;
    s[threadIdx.x] = (g < NN) ? ((deg[g] + 7) & ~7) : 0;
    __syncthreads();
    for (int o = 128; o > 0; o >>= 1) {
        if (threadIdx.x < o) s[threadIdx.x] += s[threadIdx.x + o];
        __syncthreads();
    }
    if (threadIdx.x == 0) chunkSum8[blockIdx.x] = s[0];
}

__global__ void k_scan_chunks(const int* __restrict__ chunkSum8, int* __restrict__ chunkOff8) {
    __shared__ int s[256];
    int t = threadIdx.x;
    int v = (t < NCH) ? chunkSum8[t] : 0;
    s[t] = v;
    __syncthreads();
    for (int o = 1; o < 256; o <<= 1) {
        int x = (t >= o) ? s[t - o] : 0;
        __syncthreads();
        s[t] += x;
        __syncthreads();
    }
    if (t < NCH) chunkOff8[t] = s[t] - v;
    if (t == NCH - 1) chunkOff8[NCH] = s[t];   // sentinel = padded total
}

// per-node PADDED offsets
__global__ void k_scan_write8(const int* __restrict__ deg, const int* __restrict__ chunkOff8,
                              int* __restrict__ offsets8) {
    __shared__ int s[256];
    int b = blockIdx.x, t = threadIdx.x;
    int g = b * 256 + t;
    int v = (g < NN) ? ((deg[g] + 7) & ~7) : 0;
    s[t] = v;
    __syncthreads();
    for (int o = 1; o < 256; o <<= 1) {
        int x = (t >= o) ? s[t - o] : 0;
        __syncthreads();
        s[t] += x;
        __syncthreads();
    }
    int excl = s[t] - v + chunkOff8[b];
    if (g <= NN) offsets8[g] = excl;
}

// per-bin exclusive scan over its 196 block-counts (0-based) + row total
__global__ __launch_bounds__(256) void k_scanbins(int* __restrict__ histT,
                                                  int* __restrict__ binSum) {
    __shared__ int s[256];
    int bin = blockIdx.x, t = threadIdx.x;
    int v = (t < NBLK) ? histT[bin * NBLK + t] : 0;
    s[t] = v;
    __syncthreads();
    for (int o = 1; o < 256; o <<= 1) {
        int x = (t >= o) ? s[t - o] : 0;
        __syncthreads();
        s[t] += x;
        __syncthreads();
    }
    if (t < NBLK) histT[bin * NBLK + t] = s[t] - v;
    if (t == NBLK - 1) binSum[bin] = s[t];
}

// pass C: write edges into bucket-sorted order (bases = chunkOff8 + block prefix).
// entry packs (dst<<16)|src (both < 65536) + weight bits -> 8B.
__global__ __launch_bounds__(256) void k_bucketw(const int* __restrict__ src,
                                                 const int* __restrict__ dst,
                                                 const float* __restrict__ w,
                                                 const int* __restrict__ histT,
                                                 const int* __restrict__ chunkOff8,
                                                 int2* __restrict__ bkt) {
    __shared__ int cur[NCH];
    int t = threadIdx.x, blk = blockIdx.x;
    if (t < NCH) cur[t] = histT[t * NBLK + blk] + chunkOff8[t];
    __syncthreads();
    int base = blk * EPB;
    #pragma unroll
    for (int i = 0; i < EPB / 256; ++i) {
        int e = base + i * 256 + t;
        if (e < NE) {
            int d = dst[e];
            int p = atomicAdd(&cur[d >> 8], 1);
            bkt[p] = make_int2((d << 16) | src[e], __float_as_int(w[e]));
        }
    }
}

// pass D: within-bucket -> per-node padded-CSR order + pad-fill (fused)
__global__ __launch_bounds__(256) void k_place2(const int2* __restrict__ bkt,
                                                const int* __restrict__ chunkOff8,
                                                const int* __restrict__ binSum,
                                                const int* __restrict__ offsets8,
                                                int2* __restrict__ pedge) {
    __shared__ int ncur[256];
    int t = threadIdx.x, b = blockIdx.x;
    int node = b * 256 + t;
    ncur[t] = (node < NN) ? offsets8[node] : 0;
    __syncthreads();
    int e0 = chunkOff8[b], e1 = e0 + binSum[b];
    for (int e = e0 + t; e < e1; e += 256) {
        int2 v = bkt[e];
        int d = ((unsigned)v.x) >> 16;
        int p = atomicAdd(&ncur[d & 255], 1);
        pedge[p] = v;
    }
    __syncthreads();
    // pad fill: cursors ended at offsets8[node]+deg[node]
    if (node < NN) {
        int p0 = ncur[t];
        int p1 = offsets8[node + 1];
        for (int p = p0; p < p1; ++p) pedge[p] = make_int2(0, 0);
    }
}

// ---------------- weight transpose + bf16 convert (one-time, tiny) ----------------

__global__ void k_convW(const float* __restrict__ hw, const float* __restrict__ mw_,
                        const float* __restrict__ lw,
                        unsigned short* __restrict__ Wht, unsigned short* __restrict__ Wmlt) {
    int idx = blockIdx.x * 256 + threadIdx.x;
    if (idx < 256 * 256) {
        int n = idx >> 8, k = idx & 255;
        Wht[(size_t)n * 256 + k] = f2b(hw[(size_t)k * 256 + n]);
    }
    if (idx < 128 * 256) {
        int n = idx >> 8, k = idx & 255;
        float v = (n < 64) ? mw_[(size_t)k * 64 + n] : lw[(size_t)k * 64 + (n - 64)];
        Wmlt[(size_t)n * 256 + k] = f2b(v);
    }
}

// ---------------- pipelined MFMA GEMM: 128x128 tile, 4 waves, reg-prefetch (T14) ----------
// AM: 0 = A f32 (convert on the fly); 1 = A bf16; 3 = A int8 (dequant + hbias + relu)
// EM: 3 = int8 out (runtime ldOut); 4 = bf16 + region bias (ld 128)

template <int AM>
__device__ __forceinline__ void ld_A(const void* __restrict__ Ap, int gr, int k0, int h,
                                     uint4* raw) {
    if (AM == 0) {
        const float* A = (const float*)Ap;
        #pragma unroll
        for (int i = 0; i < 8; ++i)
            raw[i] = (gr < NN) ? *reinterpret_cast<const uint4*>(&A[(size_t)gr * KD + k0 + h * 32 + i * 4])
                               : make_uint4(0, 0, 0, 0);
    } else if (AM == 1) {
        const unsigned short* A = (const unsigned short*)Ap;
        #pragma unroll
        for (int i = 0; i < 4; ++i)
            raw[i] = (gr < NN) ? *reinterpret_cast<const uint4*>(&A[(size_t)gr * KD + k0 + h * 32 + i * 8])
                               : make_uint4(0, 0, 0, 0);
    } else {
        const signed char* A = (const signed char*)Ap;
        #pragma unroll
        for (int i = 0; i < 2; ++i)
            raw[i] = (gr < NN) ? *reinterpret_cast<const uint4*>(&A[(size_t)gr * KD + k0 + h * 32 + i * 16])
                               : make_uint4(0, 0, 0, 0);
    }
}

template <int AM>
__device__ __forceinline__ void st_A(unsigned short* __restrict__ As, const uint4* raw,
                                     int r, int h, int kst, const float* __restrict__ hbias) {
    unsigned short tmp[32];
    if (AM == 0) {
        const float* f = (const float*)raw;
        #pragma unroll
        for (int i = 0; i < 32; ++i) tmp[i] = f2b(f[i]);
    } else if (AM == 1) {
        #pragma unroll
        for (int i = 0; i < 4; ++i) *reinterpret_cast<uint4*>(&tmp[i * 8]) = raw[i];
    } else {
        const signed char* q = (const signed char*)raw;
        #pragma unroll
        for (int i = 0; i < 8; ++i) {
            float4 hb4 = *reinterpret_cast<const float4*>(&hbias[kst + h * 32 + i * 4]);
            tmp[i * 4 + 0] = f2b(fmaxf((float)q[i * 4 + 0] * IQS + hb4.x, 0.f));
            tmp[i * 4 + 1] = f2b(fmaxf((float)q[i * 4 + 1] * IQS + hb4.y, 0.f));
            tmp[i * 4 + 2] = f2b(fmaxf((float)q[i * 4 + 2] * IQS + hb4.z, 0.f));
            tmp[i * 4 + 3] = f2b(fmaxf((float)q[i * 4 + 3] * IQS + hb4.w, 0.f));
        }
    }
    #pragma unroll
    for (int i = 0; i < 4; ++i) {
        int slot = (h * 4 + i) ^ (r & 7);
        *reinterpret_cast<uint4*>(&As[r * 64 + slot * 8]) = *reinterpret_cast<const uint4*>(&tmp[i * 8]);
    }
}

__device__ __forceinline__ void ld_B(const unsigned short* __restrict__ Bt, int n0, int r,
                                     int k0, int h, uint4* raw) {
    const unsigned short* B = Bt + (size_t)(n0 + r) * KD + k0 + h * 32;
    #pragma unroll
    for (int i = 0; i < 4; ++i) raw[i] = *reinterpret_cast<const uint4*>(B + i * 8);
}

__device__ __forceinline__ void st_B(unsigned short* __restrict__ Bs, const uint4* raw,
                                     int r, int h) {
    #pragma unroll
    for (int i = 0; i < 4; ++i) {
        int slot = (h * 4 + i) ^ (r & 7);
        *reinterpret_cast<uint4*>(&Bs[r * 64 + slot * 8]) = raw[i];
    }
}

template <int AM, int EM>
__global__ __launch_bounds__(256) void k_gemm(const void* __restrict__ Ap,
                                              const unsigned short* __restrict__ Bt,
                                              const float* __restrict__ hbias,
                                              const float* __restrict__ mbias,
                                              const float* __restrict__ lbias,
                                              void* __restrict__ Outp,
                                              int ldOut) {
    __shared__ unsigned short As[128 * 64];
    __shared__ unsigned short Bs[128 * 64];
    const int tid = threadIdx.x;
    const int row0 = blockIdx.x * 128;
    const int n0 = blockIdx.y * 128;
    const int lane = tid & 63;
    const int w = tid >> 6, wm = w >> 1, wn = w & 1;
    const int lr = lane & 15, lg = lane >> 4;
    const int r = tid >> 1;       // staging row 0..127
    const int h = tid & 1;        // k-half (32 bf16)
    const int gr = row0 + r;

    f32x4 acc[4][4] = {};
    uint4 ra[(AM == 0) ? 8 : ((AM == 1) ? 4 : 2)];
    uint4 rb[4];

    // prologue: stage K-tile 0
    ld_A<AM>(Ap, gr, 0, h, ra);
    ld_B(Bt, n0, r, 0, h, rb);
    st_A<AM>(As, ra, r, h, 0, hbias);
    st_B(Bs, rb, r, h);
    __syncthreads();

    #pragma unroll
    for (int kt = 0; kt < KD / 64; ++kt) {
        // issue next tile's global loads BEFORE compute (latency hides under MFMA)
        if (kt < KD / 64 - 1) {
            ld_A<AM>(Ap, gr, (kt + 1) * 64, h, ra);
            ld_B(Bt, n0, r, (kt + 1) * 64, h, rb);
        }
        const int sa = lr & 7;
        #pragma unroll
        for (int ks = 0; ks < 2; ++ks) {
            int slot = ks * 4 + lg;
            bf16x8 a[4], b[4];
            #pragma unroll
            for (int fm = 0; fm < 4; ++fm) {
                int rra = wm * 64 + fm * 16 + lr;
                a[fm] = *reinterpret_cast<const bf16x8*>(&As[rra * 64 + (slot ^ sa) * 8]);
            }
            #pragma unroll
            for (int fn = 0; fn < 4; ++fn) {
                int rrb = wn * 64 + fn * 16 + lr;
                b[fn] = *reinterpret_cast<const bf16x8*>(&Bs[rrb * 64 + (slot ^ sa) * 8]);
            }
            #pragma unroll
            for (int fm = 0; fm < 4; ++fm)
                #pragma unroll
                for (int fn = 0; fn < 4; ++fn)
                    acc[fm][fn] = __builtin_amdgcn_mfma_f32_16x16x32_bf16(a[fm], b[fn], acc[fm][fn], 0, 0, 0);
        }
        __syncthreads();
        if (kt < KD / 64 - 1) {
            st_A<AM>(As, ra, r, h, (kt + 1) * 64, hbias);
            st_B(Bs, rb, r, h);
            __syncthreads();
        }
    }

    // epilogue: C/D col=lane&15, row=(lane>>4)*4+reg
    #pragma unroll
    for (int fm = 0; fm < 4; ++fm) {
        #pragma unroll
        for (int j = 0; j < 4; ++j) {
            int grow = row0 + wm * 64 + fm * 16 + lg * 4 + j;
            if (grow >= NN) continue;
            #pragma unroll
            for (int fn = 0; fn < 4; ++fn) {
                int gcol = n0 + wn * 64 + fn * 16 + lr;
                float v = acc[fm][fn][j];
                if (EM == 3) {
                    ((signed char*)Outp)[(size_t)grow * ldOut + gcol] = quant8(v);
                } else {  // EM == 4
                    float b = (gcol < 64) ? mbias[gcol] : lbias[gcol - 64];
                    ((unsigned short*)Outp)[(size_t)grow * 128 + gcol] = f2b(v + b);
                }
            }
        }
    }
}

// ---------------- SpMM1 (int8 gather) + bias + relu -> hidden_g bf16 ----------------
// segments padded to multiples of 8 -> uniform unroll, no tail

__global__ __launch_bounds__(256) void k_spmm1(const int* __restrict__ off8,
                                               const int2* __restrict__ pedge,
                                               const unsigned* __restrict__ supq,   // [NN][64] u32 (4 int8)
                                               const float* __restrict__ bias,
                                               unsigned short* __restrict__ hg) {
    int lane = threadIdx.x & 63;
    int d = blockIdx.x * 4 + (threadIdx.x >> 6);
    int e0 = off8[d], e1 = off8[d + 1];
    float a0 = 0.f, a1 = 0.f, a2 = 0.f, a3 = 0.f;
    for (int e = e0; e < e1; e += 8) {
        int2 E[8];
        unsigned U[8];
        #pragma unroll
        for (int i = 0; i < 8; ++i) E[i] = pedge[e + i];
        #pragma unroll
        for (int i = 0; i < 8; ++i) U[i] = supq[(size_t)(E[i].x & 0xffff) * 64 + lane];
        #pragma unroll
        for (int i = 0; i < 8; ++i) {
            float w = __int_as_float(E[i].y);
            unsigned u = U[i];
            a0 = fmaf(w, (float)((int)(signed char)(u)), a0);
            a1 = fmaf(w, (float)((int)(signed char)(u >> 8)), a1);
            a2 = fmaf(w, (float)((int)(signed char)(u >> 16)), a2);
            a3 = fmaf(w, (float)((int)(signed char)(u >> 24)), a3);
        }
    }
    float4 b = *reinterpret_cast<const float4*>(&bias[lane * 4]);
    ushort4 o;
    o.x = f2b(fmaxf(a0 * IQS + b.x, 0.f));
    o.y = f2b(fmaxf(a1 * IQS + b.y, 0.f));
    o.z = f2b(fmaxf(a2 * IQS + b.z, 0.f));
    o.w = f2b(fmaxf(a3 * IQS + b.w, 0.f));
    reinterpret_cast<ushort4*>(hg)[(size_t)d * 64 + lane] = o;
}

// ---------------- SpMM2 (int8 gather, 128 dims) + mixture with mlp (write-once) ----------------

__global__ __launch_bounds__(256) void k_spmm2(const int* __restrict__ off8,
                                               const int2* __restrict__ pedge,
                                               const unsigned short* __restrict__ gq,  // [NN][64] u16 (2 int8)
                                               const unsigned short* __restrict__ mlp, // [NN][128] bf16
                                               const float* __restrict__ mixw,
                                               float* __restrict__ out) {
    int lane = threadIdx.x & 63;
    int d = blockIdx.x * 4 + (threadIdx.x >> 6);
    int e0 = off8[d], e1 = off8[d + 1];
    float a0 = 0.f, a1 = 0.f;
    for (int e = e0; e < e1; e += 8) {
        int2 E[8];
        unsigned short U[8];
        #pragma unroll
        for (int i = 0; i < 8; ++i) E[i] = pedge[e + i];
        #pragma unroll
        for (int i = 0; i < 8; ++i) U[i] = gq[(size_t)(E[i].x & 0xffff) * 64 + lane];
        #pragma unroll
        for (int i = 0; i < 8; ++i) {
            float w = __int_as_float(E[i].y);
            a0 = fmaf(w, (float)((int)(signed char)(U[i] & 0xff)), a0);
            a1 = fmaf(w, (float)((int)(signed char)(U[i] >> 8)), a1);
        }
    }
    float g0 = a0 * IQS, g1 = a1 * IQS;
    ushort2 mu = reinterpret_cast<const ushort2*>(mlp)[(size_t)d * 64 + lane];
    float m0 = b2f(mu.x), m1 = b2f(mu.y);
    float mw = mixw[0];
    float mr = 1.f / (1.f + expf(-mw));
    int c = lane * 2;
    if (c < 64) {
        *reinterpret_cast<float2*>(out + (size_t)d * OD + c) =
            make_float2(g0 * mw + m0 * (1.f - mw), g1 * mw + m1 * (1.f - mw));
    } else {
        *reinterpret_cast<float2*>(out + (size_t)NN * OD + (size_t)d * OD + (c - 64)) =
            make_float2(g0 * mr + m0 * (1.f - mr), g1 * mr + m1 * (1.f - mr));
    }
}

// ---------------- host ----------------

extern "C" void kernel_launch(void* const* d_in, const int* in_sizes, int n_in,
                              void* d_out, int out_size, void* d_ws, size_t ws_size,
                              hipStream_t stream) {
    const float* input = (const float*)d_in[0];
    const int*   ei    = (const int*)d_in[1];
    const float* ew    = (const float*)d_in[2];
    const float* mixw  = (const float*)d_in[3];
    const float* hw    = (const float*)d_in[4];
    const float* hb    = (const float*)d_in[5];
    const float* mw_   = (const float*)d_in[6];
    const float* mb    = (const float*)d_in[7];
    const float* lw    = (const float*)d_in[8];
    const float* lb    = (const float*)d_in[9];
    float* out = (float*)d_out;

    const int* src = ei;
    const int* dst = ei + NE;

    char* ws = (char*)d_ws;
    size_t off = 0;
    auto alloc = [&](size_t bytes) -> void* {
        void* p = ws + off;
        off += (bytes + 255) & ~(size_t)255;
        return p;
    };
    int*   deg      = (int*)alloc((size_t)NN * 4);
    int*   offsets8 = (int*)alloc((size_t)(NN + 1) * 4);
    int*   chunkSum8= (int*)alloc((size_t)NCH * 4);
    int*   chunkOff8= (int*)alloc((size_t)(NCH + 1) * 4);
    int*   binSum   = (int*)alloc((size_t)NCH * 4);
    int*   histT    = (int*)alloc((size_t)NHT * 4);
    int2*  bkt      = (int2*)alloc(((size_t)NE + 8 * NN) * 8);
    int2*  pedge    = (int2*)alloc(((size_t)NE + 8 * NN) * 8);
    unsigned short* Wht  = (unsigned short*)alloc((size_t)256 * 256 * 2);
    unsigned short* Wmlt = (unsigned short*)alloc((size_t)128 * 256 * 2);
    signed char*    supq     = (signed char*)alloc((size_t)NN * KD);        // int8 (gather + MLP A)
    unsigned short* hidden_g = (unsigned short*)alloc((size_t)NN * KD * 2);  // bf16
    signed char*    gcnq     = (signed char*)alloc((size_t)NN * 128);       // int8 (gather)
    unsigned short* mlp      = (unsigned short*)alloc((size_t)NN * 128 * 2); // bf16

    hipMemsetAsync(deg, 0, (size_t)NN * 4, stream);

    k_hist<<<NBLK, 256, 0, stream>>>(dst, histT, deg);
    k_chunk_sum8<<<NCH, 256, 0, stream>>>(deg, chunkSum8);
    k_scan_chunks<<<1, 256, 0, stream>>>(chunkSum8, chunkOff8);
    k_scan_write8<<<NCH, 256, 0, stream>>>(deg, chunkOff8, offsets8);
    k_scanbins<<<NCH, 256, 0, stream>>>(histT, binSum);
    k_bucketw<<<NBLK, 256, 0, stream>>>(src, dst, ew, histT, chunkOff8, bkt);
    k_place2<<<NCH, 256, 0, stream>>>(bkt, chunkOff8, binSum, offsets8, pedge);

    k_convW<<<256, 256, 0, stream>>>(hw, mw_, lw, Wht, Wmlt);

    int mblk = (NN + 127) / 128;
    // GEMM1: supq(int8) = bf16(input) @ hw
    k_gemm<0, 3><<<dim3(mblk, 2), 256, 0, stream>>>(input, Wht, hb, mb, lb, supq, 256);
    // SpMM1 (int8 gather) + bias + relu -> hidden_g (bf16)
    k_spmm1<<<NN / 4, 256, 0, stream>>>(offsets8, pedge, (const unsigned*)supq, hb, hidden_g);
    // GEMM2 (GCN): gcnq(int8) = hidden_g @ [mw|lw]
    k_gemm<1, 3><<<dim3(mblk, 1), 256, 0, stream>>>(hidden_g, Wmlt, hb, mb, lb, gcnq, 128);
    // GEMM2 (MLP): mlp(bf16) = relu(dequant(supq)+hb) @ [mw|lw] + [mb|lb]
    k_gemm<3, 4><<<dim3(mblk, 1), 256, 0, stream>>>(supq, Wmlt, hb, mb, lb, mlp, 128);
    // SpMM2 (int8 gather) + mixture combine with mlp -> d_out (write-once)
    k_spmm2<<<NN / 4, 256, 0, stream>>>(offsets8, pedge, (const unsigned short*)gcnq, mlp, mixw, out);
}

// Round 11
// 223.775 us; speedup vs baseline: 1.0160x; 1.0160x over previous
//
#include <hip/hip_runtime.h>
#include <math.h>

#define NN 50000
#define NE 800000
#define KD 256
#define OD 64
#define NCH ((NN + 255) / 256)   // 196 buckets/chunks of 256 nodes
#define EPB 4096                 // edges per histogram/bucket block
#define NBLK ((NE + EPB - 1) / EPB)   // 196 blocks
#define NHT (NCH * NBLK)         // histogram matrix entries (bin-major)

#define QS 32.0f      // int8 quant scale (fixed, power of 2)
#define IQS (1.0f / 32.0f)

using bf16x8 = __attribute__((ext_vector_type(8))) short;
using f32x4  = __attribute__((ext_vector_type(4))) float;

__device__ __forceinline__ unsigned short f2b(float x) {
    union { float f; unsigned u; } c; c.f = x;
    unsigned r = (c.u + 0x7FFF + ((c.u >> 16) & 1)) >> 16;
    return (unsigned short)r;
}
__device__ __forceinline__ float b2f(unsigned short b) {
    union { unsigned u; float f; } c; c.u = ((unsigned)b) << 16;
    return c.f;
}
__device__ __forceinline__ signed char quant8(float v) {
    int q = __float2int_rn(v * QS);
    q = q > 127 ? 127 : (q < -127 ? -127 : q);
    return (signed char)q;
}

// ---------------- CSR build (counting-sort, padded-to-8 segments) ----------------

__global__ __launch_bounds__(256) void k_hist(const int* __restrict__ dst,
                                              int* __restrict__ histT,
                                              int* __restrict__ deg) {
    __shared__ int bins[NCH];
    int t = threadIdx.x, blk = blockIdx.x;
    if (t < NCH) bins[t] = 0;
    __syncthreads();
    int base = blk * EPB;
    #pragma unroll
    for (int i = 0; i < EPB / 256; ++i) {
        int e = base + i * 256 + t;
        if (e < NE) {
            int d = dst[e];
            atomicAdd(&bins[d >> 8], 1);
            atomicAdd(&deg[d], 1);
        }
    }
    __syncthreads();
    if (t < NCH) histT[t * NBLK + blk] = bins[t];   // bin-major
}

__global__ void k_chunk_sum8(const int* __restrict__ deg, int* __restrict__ chunkSum8) {
    __shared__ int s[256];
    int g = blockIdx.x * 256 + threadIdx.x;
    s[threadIdx.x] = (g < NN) ? ((deg[g] + 7) & ~7) : 0;
    __syncthreads();
    for (int o = 128; o > 0; o >>= 1) {
        if (threadIdx.x < o) s[threadIdx.x] += s[threadIdx.x + o];
        __syncthreads();
    }
    if (threadIdx.x == 0) chunkSum8[blockIdx.x] = s[0];
}

__global__ void k_scan_chunks(const int* __restrict__ chunkSum8, int* __restrict__ chunkOff8) {
    __shared__ int s[256];
    int t = threadIdx.x;
    int v = (t < NCH) ? chunkSum8[t] : 0;
    s[t] = v;
    __syncthreads();
    for (int o = 1; o < 256; o <<= 1) {
        int x = (t >= o) ? s[t - o] : 0;
        __syncthreads();
        s[t] += x;
        __syncthreads();
    }
    if (t < NCH) chunkOff8[t] = s[t] - v;
    if (t == NCH - 1) chunkOff8[NCH] = s[t];   // sentinel = padded total
}

__global__ void k_scan_write8(const int* __restrict__ deg, const int* __restrict__ chunkOff8,
                              int* __restrict__ offsets8) {
    __shared__ int s[256];
    int b = blockIdx.x, t = threadIdx.x;
    int g = b * 256 + t;
    int v = (g < NN) ? ((deg[g] + 7) & ~7) : 0;
    s[t] = v;
    __syncthreads();
    for (int o = 1; o < 256; o <<= 1) {
        int x = (t >= o) ? s[t - o] : 0;
        __syncthreads();
        s[t] += x;
        __syncthreads();
    }
    int excl = s[t] - v + chunkOff8[b];
    if (g <= NN) offsets8[g] = excl;
}

__global__ __launch_bounds__(256) void k_scanbins(int* __restrict__ histT,
                                                  int* __restrict__ binSum) {
    __shared__ int s[256];
    int bin = blockIdx.x, t = threadIdx.x;
    int v = (t < NBLK) ? histT[bin * NBLK + t] : 0;
    s[t] = v;
    __syncthreads();
    for (int o = 1; o < 256; o <<= 1) {
        int x = (t >= o) ? s[t - o] : 0;
        __syncthreads();
        s[t] += x;
        __syncthreads();
    }
    if (t < NBLK) histT[bin * NBLK + t] = s[t] - v;
    if (t == NBLK - 1) binSum[bin] = s[t];
}

__global__ __launch_bounds__(256) void k_bucketw(const int* __restrict__ src,
                                                 const int* __restrict__ dst,
                                                 const float* __restrict__ w,
                                                 const int* __restrict__ histT,
                                                 const int* __restrict__ chunkOff8,
                                                 int2* __restrict__ bkt) {
    __shared__ int cur[NCH];
    int t = threadIdx.x, blk = blockIdx.x;
    if (t < NCH) cur[t] = histT[t * NBLK + blk] + chunkOff8[t];
    __syncthreads();
    int base = blk * EPB;
    #pragma unroll
    for (int i = 0; i < EPB / 256; ++i) {
        int e = base + i * 256 + t;
        if (e < NE) {
            int d = dst[e];
            int p = atomicAdd(&cur[d >> 8], 1);
            bkt[p] = make_int2((d << 16) | src[e], __float_as_int(w[e]));
        }
    }
}

// within-bucket -> per-node padded-CSR order + pad-fill (fused)
__global__ __launch_bounds__(256) void k_place2(const int2* __restrict__ bkt,
                                                const int* __restrict__ chunkOff8,
                                                const int* __restrict__ binSum,
                                                const int* __restrict__ offsets8,
                                                int2* __restrict__ pedge) {
    __shared__ int ncur[256];
    int t = threadIdx.x, b = blockIdx.x;
    int node = b * 256 + t;
    ncur[t] = (node < NN) ? offsets8[node] : 0;
    __syncthreads();
    int e0 = chunkOff8[b], e1 = e0 + binSum[b];
    for (int e = e0 + t; e < e1; e += 256) {
        int2 v = bkt[e];
        int d = ((unsigned)v.x) >> 16;
        int p = atomicAdd(&ncur[d & 255], 1);
        pedge[p] = v;
    }
    __syncthreads();
    if (node < NN) {
        int p0 = ncur[t];
        int p1 = offsets8[node + 1];
        for (int p = p0; p < p1; ++p) pedge[p] = make_int2(0, 0);
    }
}

// ---------------- weight transpose + bf16 convert (one-time, tiny) ----------------

__global__ void k_convW(const float* __restrict__ hw, const float* __restrict__ mw_,
                        const float* __restrict__ lw,
                        unsigned short* __restrict__ Wht, unsigned short* __restrict__ Wmlt) {
    int idx = blockIdx.x * 256 + threadIdx.x;
    if (idx < 256 * 256) {
        int n = idx >> 8, k = idx & 255;
        Wht[(size_t)n * 256 + k] = f2b(hw[(size_t)k * 256 + n]);
    }
    if (idx < 128 * 256) {
        int n = idx >> 8, k = idx & 255;
        float v = (n < 64) ? mw_[(size_t)k * 64 + n] : lw[(size_t)k * 64 + (n - 64)];
        Wmlt[(size_t)n * 256 + k] = f2b(v);
    }
}

// ---------------- MFMA GEMM: 128x64 block tile, 4 waves, wave-tile 64x32 ----------------
// AM: 0 = A f32 (convert on the fly); 1 = A bf16; 2 = A bf16 + hbias + relu
// EM: 2 = bf16 (ld 256) to Outp AND int8 (ld 256) to Outp2        [gemm1]
//     3 = int8 only (ld 128) to Outp                              [gemm2 GCN]
//     4 = bf16 + region bias (ld 128) to Outp                     [gemm2 MLP]

template <int AM, int EM>
__global__ __launch_bounds__(256) void k_gemm(const void* __restrict__ Ap,
                                              const unsigned short* __restrict__ Bt,
                                              const float* __restrict__ hbias,
                                              const float* __restrict__ mbias,
                                              const float* __restrict__ lbias,
                                              void* __restrict__ Outp,
                                              void* __restrict__ Outp2) {
    __shared__ unsigned short As[128 * 64];
    __shared__ unsigned short Bs[64 * 64];
    const int tid = threadIdx.x;
    const int row0 = blockIdx.x * 128;
    const int n0 = blockIdx.y * 64;
    const int lane = tid & 63;
    const int w = tid >> 6, wm = w >> 1, wn = w & 1;
    const int lr = lane & 15, lg = lane >> 4;
    const int r = tid >> 1;       // A staging row 0..127
    const int h = tid & 1;        // A k-half (32 bf16)
    const int rb2 = tid >> 2;     // B staging row 0..63
    const int q = tid & 3;        // B k-quarter (16 bf16)

    f32x4 acc[4][2] = {};

    for (int k0 = 0; k0 < KD; k0 += 64) {
        // ---- stage A (128 rows x 64 k bf16, XOR-swizzled 16B slots) ----
        {
            int gr = row0 + r;
            unsigned short tmp[32];
            if (AM == 0) {
                const float* A = (const float*)Ap;
                if (gr < NN) {
                    #pragma unroll
                    for (int i = 0; i < 8; ++i) {
                        float4 v = *reinterpret_cast<const float4*>(
                            &A[(size_t)gr * KD + k0 + h * 32 + i * 4]);
                        tmp[i * 4 + 0] = f2b(v.x); tmp[i * 4 + 1] = f2b(v.y);
                        tmp[i * 4 + 2] = f2b(v.z); tmp[i * 4 + 3] = f2b(v.w);
                    }
                } else {
                    #pragma unroll
                    for (int i = 0; i < 32; ++i) tmp[i] = 0;
                }
            } else {
                const unsigned short* A = (const unsigned short*)Ap;
                if (gr < NN) {
                    #pragma unroll
                    for (int i = 0; i < 4; ++i)
                        *reinterpret_cast<uint4*>(&tmp[i * 8]) =
                            *reinterpret_cast<const uint4*>(&A[(size_t)gr * KD + k0 + h * 32 + i * 8]);
                    if (AM == 2) {
                        #pragma unroll
                        for (int i = 0; i < 8; ++i) {
                            float4 hb4 = *reinterpret_cast<const float4*>(&hbias[k0 + h * 32 + i * 4]);
                            tmp[i * 4 + 0] = f2b(fmaxf(b2f(tmp[i * 4 + 0]) + hb4.x, 0.f));
                            tmp[i * 4 + 1] = f2b(fmaxf(b2f(tmp[i * 4 + 1]) + hb4.y, 0.f));
                            tmp[i * 4 + 2] = f2b(fmaxf(b2f(tmp[i * 4 + 2]) + hb4.z, 0.f));
                            tmp[i * 4 + 3] = f2b(fmaxf(b2f(tmp[i * 4 + 3]) + hb4.w, 0.f));
                        }
                    }
                } else {
                    #pragma unroll
                    for (int i = 0; i < 32; ++i) tmp[i] = 0;
                }
            }
            #pragma unroll
            for (int i = 0; i < 4; ++i) {
                int slot = (h * 4 + i) ^ (r & 7);
                *reinterpret_cast<uint4*>(&As[r * 64 + slot * 8]) =
                    *reinterpret_cast<const uint4*>(&tmp[i * 8]);
            }
        }
        // ---- stage B (64 rows x 64 k; Bt is [N][K] bf16 row-major) ----
        {
            const unsigned short* B = Bt + (size_t)(n0 + rb2) * KD + k0 + q * 16;
            uint4 u0 = *reinterpret_cast<const uint4*>(B);
            uint4 u1 = *reinterpret_cast<const uint4*>(B + 8);
            int s0 = (q * 2) ^ (rb2 & 7);
            int s1 = (q * 2 + 1) ^ (rb2 & 7);
            *reinterpret_cast<uint4*>(&Bs[rb2 * 64 + s0 * 8]) = u0;
            *reinterpret_cast<uint4*>(&Bs[rb2 * 64 + s1 * 8]) = u1;
        }
        __syncthreads();
        // ---- MFMA: wave 64x32, fragments 4x2, 2 K-slices of 32 ----
        #pragma unroll
        for (int ks = 0; ks < 2; ++ks) {
            int slot = ks * 4 + lg;
            bf16x8 a[4], b[2];
            #pragma unroll
            for (int fm = 0; fm < 4; ++fm) {
                int ra = wm * 64 + fm * 16 + lr;
                a[fm] = *reinterpret_cast<const bf16x8*>(&As[ra * 64 + ((slot ^ (ra & 7))) * 8]);
            }
            #pragma unroll
            for (int fn = 0; fn < 2; ++fn) {
                int rbr = wn * 32 + fn * 16 + lr;
                b[fn] = *reinterpret_cast<const bf16x8*>(&Bs[rbr * 64 + ((slot ^ (rbr & 7))) * 8]);
            }
            #pragma unroll
            for (int fm = 0; fm < 4; ++fm)
                #pragma unroll
                for (int fn = 0; fn < 2; ++fn)
                    acc[fm][fn] = __builtin_amdgcn_mfma_f32_16x16x32_bf16(a[fm], b[fn], acc[fm][fn], 0, 0, 0);
        }
        __syncthreads();
    }
    // ---- epilogue: C/D col=lane&15, row=(lane>>4)*4+reg ----
    #pragma unroll
    for (int fm = 0; fm < 4; ++fm) {
        #pragma unroll
        for (int j = 0; j < 4; ++j) {
            int grow = row0 + wm * 64 + fm * 16 + lg * 4 + j;
            if (grow >= NN) continue;
            #pragma unroll
            for (int fn = 0; fn < 2; ++fn) {
                int gcol = n0 + wn * 32 + fn * 16 + lr;
                float v = acc[fm][fn][j];
                if (EM == 2) {
                    ((unsigned short*)Outp)[(size_t)grow * 256 + gcol] = f2b(v);
                    ((signed char*)Outp2)[(size_t)grow * 256 + gcol] = quant8(v);
                } else if (EM == 3) {
                    ((signed char*)Outp)[(size_t)grow * 128 + gcol] = quant8(v);
                } else {  // EM == 4
                    float b = (gcol < 64) ? mbias[gcol] : lbias[gcol - 64];
                    ((unsigned short*)Outp)[(size_t)grow * 128 + gcol] = f2b(v + b);
                }
            }
        }
    }
}

// ---------------- SpMM1 (int8 gather) + bias + relu -> hidden_g bf16 ----------------

__global__ __launch_bounds__(256) void k_spmm1(const int* __restrict__ off8,
                                               const int2* __restrict__ pedge,
                                               const unsigned* __restrict__ supq,   // [NN][64] u32 (4 int8)
                                               const float* __restrict__ bias,
                                               unsigned short* __restrict__ hg) {
    int lane = threadIdx.x & 63;
    int d = blockIdx.x * 4 + (threadIdx.x >> 6);
    int e0 = off8[d], e1 = off8[d + 1];
    float a0 = 0.f, a1 = 0.f, a2 = 0.f, a3 = 0.f;
    for (int e = e0; e < e1; e += 8) {
        int2 E[8];
        unsigned U[8];
        #pragma unroll
        for (int i = 0; i < 8; ++i) E[i] = pedge[e + i];
        #pragma unroll
        for (int i = 0; i < 8; ++i) U[i] = supq[(size_t)(E[i].x & 0xffff) * 64 + lane];
        #pragma unroll
        for (int i = 0; i < 8; ++i) {
            float w = __int_as_float(E[i].y);
            unsigned u = U[i];
            a0 = fmaf(w, (float)((int)(signed char)(u)), a0);
            a1 = fmaf(w, (float)((int)(signed char)(u >> 8)), a1);
            a2 = fmaf(w, (float)((int)(signed char)(u >> 16)), a2);
            a3 = fmaf(w, (float)((int)(signed char)(u >> 24)), a3);
        }
    }
    float4 b = *reinterpret_cast<const float4*>(&bias[lane * 4]);
    ushort4 o;
    o.x = f2b(fmaxf(a0 * IQS + b.x, 0.f));
    o.y = f2b(fmaxf(a1 * IQS + b.y, 0.f));
    o.z = f2b(fmaxf(a2 * IQS + b.z, 0.f));
    o.w = f2b(fmaxf(a3 * IQS + b.w, 0.f));
    reinterpret_cast<ushort4*>(hg)[(size_t)d * 64 + lane] = o;
}

// ---------------- SpMM2 (int8 gather, 128 dims) + mixture with mlp (write-once) ----------------

__global__ __launch_bounds__(256) void k_spmm2(const int* __restrict__ off8,
                                               const int2* __restrict__ pedge,
                                               const unsigned short* __restrict__ gq,  // [NN][64] u16 (2 int8)
                                               const unsigned short* __restrict__ mlp, // [NN][128] bf16
                                               const float* __restrict__ mixw,
                                               float* __restrict__ out) {
    int lane = threadIdx.x & 63;
    int d = blockIdx.x * 4 + (threadIdx.x >> 6);
    int e0 = off8[d], e1 = off8[d + 1];
    float a0 = 0.f, a1 = 0.f;
    for (int e = e0; e < e1; e += 8) {
        int2 E[8];
        unsigned short U[8];
        #pragma unroll
        for (int i = 0; i < 8; ++i) E[i] = pedge[e + i];
        #pragma unroll
        for (int i = 0; i < 8; ++i) U[i] = gq[(size_t)(E[i].x & 0xffff) * 64 + lane];
        #pragma unroll
        for (int i = 0; i < 8; ++i) {
            float w = __int_as_float(E[i].y);
            a0 = fmaf(w, (float)((int)(signed char)(U[i] & 0xff)), a0);
            a1 = fmaf(w, (float)((int)(signed char)(U[i] >> 8)), a1);
        }
    }
    float g0 = a0 * IQS, g1 = a1 * IQS;
    ushort2 mu = reinterpret_cast<const ushort2*>(mlp)[(size_t)d * 64 + lane];
    float m0 = b2f(mu.x), m1 = b2f(mu.y);
    float mw = mixw[0];
    float mr = 1.f / (1.f + expf(-mw));
    int c = lane * 2;
    if (c < 64) {
        *reinterpret_cast<float2*>(out + (size_t)d * OD + c) =
            make_float2(g0 * mw + m0 * (1.f - mw), g1 * mw + m1 * (1.f - mw));
    } else {
        *reinterpret_cast<float2*>(out + (size_t)NN * OD + (size_t)d * OD + (c - 64)) =
            make_float2(g0 * mr + m0 * (1.f - mr), g1 * mr + m1 * (1.f - mr));
    }
}

// ---------------- host ----------------

extern "C" void kernel_launch(void* const* d_in, const int* in_sizes, int n_in,
                              void* d_out, int out_size, void* d_ws, size_t ws_size,
                              hipStream_t stream) {
    const float* input = (const float*)d_in[0];
    const int*   ei    = (const int*)d_in[1];
    const float* ew    = (const float*)d_in[2];
    const float* mixw  = (const float*)d_in[3];
    const float* hw    = (const float*)d_in[4];
    const float* hb    = (const float*)d_in[5];
    const float* mw_   = (const float*)d_in[6];
    const float* mb    = (const float*)d_in[7];
    const float* lw    = (const float*)d_in[8];
    const float* lb    = (const float*)d_in[9];
    float* out = (float*)d_out;

    const int* src = ei;
    const int* dst = ei + NE;

    char* ws = (char*)d_ws;
    size_t off = 0;
    auto alloc = [&](size_t bytes) -> void* {
        void* p = ws + off;
        off += (bytes + 255) & ~(size_t)255;
        return p;
    };
    int*   deg      = (int*)alloc((size_t)NN * 4);
    int*   offsets8 = (int*)alloc((size_t)(NN + 1) * 4);
    int*   chunkSum8= (int*)alloc((size_t)NCH * 4);
    int*   chunkOff8= (int*)alloc((size_t)(NCH + 1) * 4);
    int*   binSum   = (int*)alloc((size_t)NCH * 4);
    int*   histT    = (int*)alloc((size_t)NHT * 4);
    int2*  bkt      = (int2*)alloc(((size_t)NE + 8 * NN) * 8);
    int2*  pedge    = (int2*)alloc(((size_t)NE + 8 * NN) * 8);
    unsigned short* Wht  = (unsigned short*)alloc((size_t)256 * 256 * 2);
    unsigned short* Wmlt = (unsigned short*)alloc((size_t)128 * 256 * 2);
    unsigned short* support  = (unsigned short*)alloc((size_t)NN * KD * 2);  // bf16 (MLP path)
    signed char*    supq     = (signed char*)alloc((size_t)NN * KD);        // int8 (gather)
    unsigned short* hidden_g = (unsigned short*)alloc((size_t)NN * KD * 2);  // bf16
    signed char*    gcnq     = (signed char*)alloc((size_t)NN * 128);       // int8 (gather)
    unsigned short* mlp      = (unsigned short*)alloc((size_t)NN * 128 * 2); // bf16

    hipMemsetAsync(deg, 0, (size_t)NN * 4, stream);

    k_hist<<<NBLK, 256, 0, stream>>>(dst, histT, deg);
    k_chunk_sum8<<<NCH, 256, 0, stream>>>(deg, chunkSum8);
    k_scan_chunks<<<1, 256, 0, stream>>>(chunkSum8, chunkOff8);
    k_scan_write8<<<NCH, 256, 0, stream>>>(deg, chunkOff8, offsets8);
    k_scanbins<<<NCH, 256, 0, stream>>>(histT, binSum);
    k_bucketw<<<NBLK, 256, 0, stream>>>(src, dst, ew, histT, chunkOff8, bkt);
    k_place2<<<NCH, 256, 0, stream>>>(bkt, chunkOff8, binSum, offsets8, pedge);

    k_convW<<<256, 256, 0, stream>>>(hw, mw_, lw, Wht, Wmlt);

    int mblk = (NN + 127) / 128;   // 391
    // GEMM1: support(bf16) + supq(int8) = bf16(input) @ hw   (N=256 -> y=4)
    k_gemm<0, 2><<<dim3(mblk, 4), 256, 0, stream>>>(input, Wht, hb, mb, lb, support, supq);
    // SpMM1 (int8 gather) + bias + relu -> hidden_g (bf16)
    k_spmm1<<<NN / 4, 256, 0, stream>>>(offsets8, pedge, (const unsigned*)supq, hb, hidden_g);
    // GEMM2 (GCN): gcnq(int8) = hidden_g @ [mw|lw]   (N=128 -> y=2)
    k_gemm<1, 3><<<dim3(mblk, 2), 256, 0, stream>>>(hidden_g, Wmlt, hb, mb, lb, gcnq, nullptr);
    // GEMM2 (MLP): mlp(bf16) = relu(support+hb) @ [mw|lw] + [mb|lb]
    k_gemm<2, 4><<<dim3(mblk, 2), 256, 0, stream>>>(support, Wmlt, hb, mb, lb, mlp, nullptr);
    // SpMM2 (int8 gather) + mixture combine with mlp -> d_out (write-once)
    k_spmm2<<<NN / 4, 256, 0, stream>>>(offsets8, pedge, (const unsigned short*)gcnq, mlp, mixw, out);
}

// Round 12
// 196.241 us; speedup vs baseline: 1.1586x; 1.1403x over previous
//
#include <hip/hip_runtime.h>
#include <math.h>

#define NN 50000
#define NE 800000
#define KD 256
#define OD 64
#define NCH ((NN + 255) / 256)   // 196 buckets/chunks of 256 nodes
#define EPB 4096                 // edges per histogram/bucket block
#define NBLK ((NE + EPB - 1) / EPB)   // 196 blocks
#define NHT (NCH * NBLK)         // histogram matrix entries (bin-major)

#define QS 32.0f      // int8 quant scale (fixed, power of 2)
#define IQS (1.0f / 32.0f)

using bf16x8 = __attribute__((ext_vector_type(8))) short;
using f32x4  = __attribute__((ext_vector_type(4))) float;

__device__ __forceinline__ unsigned short f2b(float x) {
    union { float f; unsigned u; } c; c.f = x;
    unsigned r = (c.u + 0x7FFF + ((c.u >> 16) & 1)) >> 16;
    return (unsigned short)r;
}
__device__ __forceinline__ float b2f(unsigned short b) {
    union { unsigned u; float f; } c; c.u = ((unsigned)b) << 16;
    return c.f;
}
__device__ __forceinline__ signed char quant8(float v) {
    int q = __float2int_rn(v * QS);
    q = q > 127 ? 127 : (q < -127 ? -127 : q);
    return (signed char)q;
}

// ---------------- CSR build (counting-sort, padded-to-8 segments) ----------------

__global__ __launch_bounds__(256) void k_hist(const int* __restrict__ dst,
                                              int* __restrict__ histT,
                                              int* __restrict__ deg) {
    __shared__ int bins[NCH];
    int t = threadIdx.x, blk = blockIdx.x;
    if (t < NCH) bins[t] = 0;
    __syncthreads();
    int base = blk * EPB;
    #pragma unroll
    for (int i = 0; i < EPB / 256; ++i) {
        int e = base + i * 256 + t;
        if (e < NE) {
            int d = dst[e];
            atomicAdd(&bins[d >> 8], 1);
            atomicAdd(&deg[d], 1);
        }
    }
    __syncthreads();
    if (t < NCH) histT[t * NBLK + blk] = bins[t];   // bin-major
}

__global__ void k_chunk_sum8(const int* __restrict__ deg, int* __restrict__ chunkSum8) {
    __shared__ int s[256];
    int g = blockIdx.x * 256 + threadIdx.x;
    s[threadIdx.x] = (g < NN) ? ((deg[g] + 7) & ~7) : 0;
    __syncthreads();
    for (int o = 128; o > 0; o >>= 1) {
        if (threadIdx.x < o) s[threadIdx.x] += s[threadIdx.x + o];
        __syncthreads();
    }
    if (threadIdx.x == 0) chunkSum8[blockIdx.x] = s[0];
}

__global__ void k_scan_chunks(const int* __restrict__ chunkSum8, int* __restrict__ chunkOff8) {
    __shared__ int s[256];
    int t = threadIdx.x;
    int v = (t < NCH) ? chunkSum8[t] : 0;
    s[t] = v;
    __syncthreads();
    for (int o = 1; o < 256; o <<= 1) {
        int x = (t >= o) ? s[t - o] : 0;
        __syncthreads();
        s[t] += x;
        __syncthreads();
    }
    if (t < NCH) chunkOff8[t] = s[t] - v;
    if (t == NCH - 1) chunkOff8[NCH] = s[t];   // sentinel = padded total
}

__global__ void k_scan_write8(const int* __restrict__ deg, const int* __restrict__ chunkOff8,
                              int* __restrict__ offsets8) {
    __shared__ int s[256];
    int b = blockIdx.x, t = threadIdx.x;
    int g = b * 256 + t;
    int v = (g < NN) ? ((deg[g] + 7) & ~7) : 0;
    s[t] = v;
    __syncthreads();
    for (int o = 1; o < 256; o <<= 1) {
        int x = (t >= o) ? s[t - o] : 0;
        __syncthreads();
        s[t] += x;
        __syncthreads();
    }
    int excl = s[t] - v + chunkOff8[b];
    if (g <= NN) offsets8[g] = excl;
}

__global__ __launch_bounds__(256) void k_scanbins(int* __restrict__ histT,
                                                  int* __restrict__ binSum) {
    __shared__ int s[256];
    int bin = blockIdx.x, t = threadIdx.x;
    int v = (t < NBLK) ? histT[bin * NBLK + t] : 0;
    s[t] = v;
    __syncthreads();
    for (int o = 1; o < 256; o <<= 1) {
        int x = (t >= o) ? s[t - o] : 0;
        __syncthreads();
        s[t] += x;
        __syncthreads();
    }
    if (t < NBLK) histT[bin * NBLK + t] = s[t] - v;
    if (t == NBLK - 1) binSum[bin] = s[t];
}

__global__ __launch_bounds__(256) void k_bucketw(const int* __restrict__ src,
                                                 const int* __restrict__ dst,
                                                 const float* __restrict__ w,
                                                 const int* __restrict__ histT,
                                                 const int* __restrict__ chunkOff8,
                                                 int2* __restrict__ bkt) {
    __shared__ int cur[NCH];
    int t = threadIdx.x, blk = blockIdx.x;
    if (t < NCH) cur[t] = histT[t * NBLK + blk] + chunkOff8[t];
    __syncthreads();
    int base = blk * EPB;
    #pragma unroll
    for (int i = 0; i < EPB / 256; ++i) {
        int e = base + i * 256 + t;
        if (e < NE) {
            int d = dst[e];
            int p = atomicAdd(&cur[d >> 8], 1);
            bkt[p] = make_int2((d << 16) | src[e], __float_as_int(w[e]));
        }
    }
}

// within-bucket -> per-node padded-CSR order + pad-fill (fused)
__global__ __launch_bounds__(256) void k_place2(const int2* __restrict__ bkt,
                                                const int* __restrict__ chunkOff8,
                                                const int* __restrict__ binSum,
                                                const int* __restrict__ offsets8,
                                                int2* __restrict__ pedge) {
    __shared__ int ncur[256];
    int t = threadIdx.x, b = blockIdx.x;
    int node = b * 256 + t;
    ncur[t] = (node < NN) ? offsets8[node] : 0;
    __syncthreads();
    int e0 = chunkOff8[b], e1 = e0 + binSum[b];
    for (int e = e0 + t; e < e1; e += 256) {
        int2 v = bkt[e];
        int d = ((unsigned)v.x) >> 16;
        int p = atomicAdd(&ncur[d & 255], 1);
        pedge[p] = v;
    }
    __syncthreads();
    if (node < NN) {
        int p0 = ncur[t];
        int p1 = offsets8[node + 1];
        for (int p = p0; p < p1; ++p) pedge[p] = make_int2(0, 0);
    }
}

// ---------------- weight transpose + bf16 convert (one-time, tiny) ----------------

__global__ void k_convW(const float* __restrict__ hw, const float* __restrict__ mw_,
                        const float* __restrict__ lw,
                        unsigned short* __restrict__ Wht, unsigned short* __restrict__ Wmlt) {
    int idx = blockIdx.x * 256 + threadIdx.x;
    if (idx < 256 * 256) {
        int n = idx >> 8, k = idx & 255;
        Wht[(size_t)n * 256 + k] = f2b(hw[(size_t)k * 256 + n]);
    }
    if (idx < 128 * 256) {
        int n = idx >> 8, k = idx & 255;
        float v = (n < 64) ? mw_[(size_t)k * 64 + n] : lw[(size_t)k * 64 + (n - 64)];
        Wmlt[(size_t)n * 256 + k] = f2b(v);
    }
}

// ---------------- MFMA GEMM: 64x128 block tile, 4 waves, wave-tile 32x64 ----------------
// AM: 0 = A f32 (convert on the fly); 1 = A bf16; 2 = A bf16 + hbias + relu
// EM: 2 = bf16 (ld 256) to Outp AND int8 (ld 256) to Outp2        [gemm1]
//     3 = int8 only (ld 128) to Outp                              [gemm2 GCN]
//     4 = bf16 + region bias (ld 128) to Outp                     [gemm2 MLP]

template <int AM, int EM>
__global__ __launch_bounds__(256) void k_gemm(const void* __restrict__ Ap,
                                              const unsigned short* __restrict__ Bt,
                                              const float* __restrict__ hbias,
                                              const float* __restrict__ mbias,
                                              const float* __restrict__ lbias,
                                              void* __restrict__ Outp,
                                              void* __restrict__ Outp2) {
    __shared__ unsigned short As[64 * 64];
    __shared__ unsigned short Bs[128 * 64];
    const int tid = threadIdx.x;
    const int row0 = blockIdx.x * 64;
    const int n0 = blockIdx.y * 128;
    const int lane = tid & 63;
    const int w = tid >> 6, wm = w >> 1, wn = w & 1;
    const int lr = lane & 15, lg = lane >> 4;
    const int rA = tid >> 2;      // A staging row 0..63
    const int qA = tid & 3;       // A k-quarter (16 bf16)
    const int rB = tid >> 1;      // B staging row 0..127
    const int hB = tid & 1;       // B k-half (32 bf16)

    f32x4 acc[2][4] = {};

    for (int k0 = 0; k0 < KD; k0 += 64) {
        // ---- stage A (64 rows x 64 k bf16, XOR-swizzled 16B slots) ----
        {
            int gr = row0 + rA;
            unsigned short tmp[16];
            if (AM == 0) {
                const float* A = (const float*)Ap;
                if (gr < NN) {
                    #pragma unroll
                    for (int i = 0; i < 4; ++i) {
                        float4 v = *reinterpret_cast<const float4*>(
                            &A[(size_t)gr * KD + k0 + qA * 16 + i * 4]);
                        tmp[i * 4 + 0] = f2b(v.x); tmp[i * 4 + 1] = f2b(v.y);
                        tmp[i * 4 + 2] = f2b(v.z); tmp[i * 4 + 3] = f2b(v.w);
                    }
                } else {
                    #pragma unroll
                    for (int i = 0; i < 16; ++i) tmp[i] = 0;
                }
            } else {
                const unsigned short* A = (const unsigned short*)Ap;
                if (gr < NN) {
                    *reinterpret_cast<uint4*>(&tmp[0]) =
                        *reinterpret_cast<const uint4*>(&A[(size_t)gr * KD + k0 + qA * 16]);
                    *reinterpret_cast<uint4*>(&tmp[8]) =
                        *reinterpret_cast<const uint4*>(&A[(size_t)gr * KD + k0 + qA * 16 + 8]);
                    if (AM == 2) {
                        #pragma unroll
                        for (int i = 0; i < 4; ++i) {
                            float4 hb4 = *reinterpret_cast<const float4*>(&hbias[k0 + qA * 16 + i * 4]);
                            tmp[i * 4 + 0] = f2b(fmaxf(b2f(tmp[i * 4 + 0]) + hb4.x, 0.f));
                            tmp[i * 4 + 1] = f2b(fmaxf(b2f(tmp[i * 4 + 1]) + hb4.y, 0.f));
                            tmp[i * 4 + 2] = f2b(fmaxf(b2f(tmp[i * 4 + 2]) + hb4.z, 0.f));
                            tmp[i * 4 + 3] = f2b(fmaxf(b2f(tmp[i * 4 + 3]) + hb4.w, 0.f));
                        }
                    }
                } else {
                    #pragma unroll
                    for (int i = 0; i < 16; ++i) tmp[i] = 0;
                }
            }
            int s0 = (qA * 2) ^ (rA & 7);
            int s1 = (qA * 2 + 1) ^ (rA & 7);
            *reinterpret_cast<uint4*>(&As[rA * 64 + s0 * 8]) = *reinterpret_cast<const uint4*>(&tmp[0]);
            *reinterpret_cast<uint4*>(&As[rA * 64 + s1 * 8]) = *reinterpret_cast<const uint4*>(&tmp[8]);
        }
        // ---- stage B (128 rows x 64 k; Bt is [N][K] bf16 row-major) ----
        {
            const unsigned short* B = Bt + (size_t)(n0 + rB) * KD + k0 + hB * 32;
            #pragma unroll
            for (int i = 0; i < 4; ++i) {
                uint4 u = *reinterpret_cast<const uint4*>(B + i * 8);
                int slot = (hB * 4 + i) ^ (rB & 7);
                *reinterpret_cast<uint4*>(&Bs[rB * 64 + slot * 8]) = u;
            }
        }
        __syncthreads();
        // ---- MFMA: wave 32x64, fragments 2x4, 2 K-slices of 32 ----
        #pragma unroll
        for (int ks = 0; ks < 2; ++ks) {
            int slot = ks * 4 + lg;
            bf16x8 a[2], b[4];
            #pragma unroll
            for (int fm = 0; fm < 2; ++fm) {
                int ra = wm * 32 + fm * 16 + lr;
                a[fm] = *reinterpret_cast<const bf16x8*>(&As[ra * 64 + ((slot ^ (ra & 7))) * 8]);
            }
            #pragma unroll
            for (int fn = 0; fn < 4; ++fn) {
                int rb = wn * 64 + fn * 16 + lr;
                b[fn] = *reinterpret_cast<const bf16x8*>(&Bs[rb * 64 + ((slot ^ (rb & 7))) * 8]);
            }
            #pragma unroll
            for (int fm = 0; fm < 2; ++fm)
                #pragma unroll
                for (int fn = 0; fn < 4; ++fn)
                    acc[fm][fn] = __builtin_amdgcn_mfma_f32_16x16x32_bf16(a[fm], b[fn], acc[fm][fn], 0, 0, 0);
        }
        __syncthreads();
    }
    // ---- epilogue: C/D col=lane&15, row=(lane>>4)*4+reg ----
    #pragma unroll
    for (int fm = 0; fm < 2; ++fm) {
        #pragma unroll
        for (int j = 0; j < 4; ++j) {
            int grow = row0 + wm * 32 + fm * 16 + lg * 4 + j;
            if (grow >= NN) continue;
            #pragma unroll
            for (int fn = 0; fn < 4; ++fn) {
                int gcol = n0 + wn * 64 + fn * 16 + lr;
                float v = acc[fm][fn][j];
                if (EM == 2) {
                    ((unsigned short*)Outp)[(size_t)grow * 256 + gcol] = f2b(v);
                    ((signed char*)Outp2)[(size_t)grow * 256 + gcol] = quant8(v);
                } else if (EM == 3) {
                    ((signed char*)Outp)[(size_t)grow * 128 + gcol] = quant8(v);
                } else {  // EM == 4
                    float b = (gcol < 64) ? mbias[gcol] : lbias[gcol - 64];
                    ((unsigned short*)Outp)[(size_t)grow * 128 + gcol] = f2b(v + b);
                }
            }
        }
    }
}

// ---------------- SpMM1 (int8 gather) + bias + relu -> hidden_g bf16 ----------------

__global__ __launch_bounds__(256) void k_spmm1(const int* __restrict__ off8,
                                               const int2* __restrict__ pedge,
                                               const unsigned* __restrict__ supq,   // [NN][64] u32 (4 int8)
                                               const float* __restrict__ bias,
                                               unsigned short* __restrict__ hg) {
    int lane = threadIdx.x & 63;
    int d = blockIdx.x * 4 + (threadIdx.x >> 6);
    int e0 = off8[d], e1 = off8[d + 1];
    float a0 = 0.f, a1 = 0.f, a2 = 0.f, a3 = 0.f;
    for (int e = e0; e < e1; e += 8) {
        int2 E[8];
        unsigned U[8];
        #pragma unroll
        for (int i = 0; i < 8; ++i) E[i] = pedge[e + i];
        #pragma unroll
        for (int i = 0; i < 8; ++i) U[i] = supq[(size_t)(E[i].x & 0xffff) * 64 + lane];
        #pragma unroll
        for (int i = 0; i < 8; ++i) {
            float w = __int_as_float(E[i].y);
            unsigned u = U[i];
            a0 = fmaf(w, (float)((int)(signed char)(u)), a0);
            a1 = fmaf(w, (float)((int)(signed char)(u >> 8)), a1);
            a2 = fmaf(w, (float)((int)(signed char)(u >> 16)), a2);
            a3 = fmaf(w, (float)((int)(signed char)(u >> 24)), a3);
        }
    }
    float4 b = *reinterpret_cast<const float4*>(&bias[lane * 4]);
    ushort4 o;
    o.x = f2b(fmaxf(a0 * IQS + b.x, 0.f));
    o.y = f2b(fmaxf(a1 * IQS + b.y, 0.f));
    o.z = f2b(fmaxf(a2 * IQS + b.z, 0.f));
    o.w = f2b(fmaxf(a3 * IQS + b.w, 0.f));
    reinterpret_cast<ushort4*>(hg)[(size_t)d * 64 + lane] = o;
}

// ---------------- SpMM2 (int8 gather, 128 dims) + mixture with mlp (write-once) ----------------

__global__ __launch_bounds__(256) void k_spmm2(const int* __restrict__ off8,
                                               const int2* __restrict__ pedge,
                                               const unsigned short* __restrict__ gq,  // [NN][64] u16 (2 int8)
                                               const unsigned short* __restrict__ mlp, // [NN][128] bf16
                                               const float* __restrict__ mixw,
                                               float* __restrict__ out) {
    int lane = threadIdx.x & 63;
    int d = blockIdx.x * 4 + (threadIdx.x >> 6);
    int e0 = off8[d], e1 = off8[d + 1];
    float a0 = 0.f, a1 = 0.f;
    for (int e = e0; e < e1; e += 8) {
        int2 E[8];
        unsigned short U[8];
        #pragma unroll
        for (int i = 0; i < 8; ++i) E[i] = pedge[e + i];
        #pragma unroll
        for (int i = 0; i < 8; ++i) U[i] = gq[(size_t)(E[i].x & 0xffff) * 64 + lane];
        #pragma unroll
        for (int i = 0; i < 8; ++i) {
            float w = __int_as_float(E[i].y);
            a0 = fmaf(w, (float)((int)(signed char)(U[i] & 0xff)), a0);
            a1 = fmaf(w, (float)((int)(signed char)(U[i] >> 8)), a1);
        }
    }
    float g0 = a0 * IQS, g1 = a1 * IQS;
    ushort2 mu = reinterpret_cast<const ushort2*>(mlp)[(size_t)d * 64 + lane];
    float m0 = b2f(mu.x), m1 = b2f(mu.y);
    float mw = mixw[0];
    float mr = 1.f / (1.f + expf(-mw));
    int c = lane * 2;
    if (c < 64) {
        *reinterpret_cast<float2*>(out + (size_t)d * OD + c) =
            make_float2(g0 * mw + m0 * (1.f - mw), g1 * mw + m1 * (1.f - mw));
    } else {
        *reinterpret_cast<float2*>(out + (size_t)NN * OD + (size_t)d * OD + (c - 64)) =
            make_float2(g0 * mr + m0 * (1.f - mr), g1 * mr + m1 * (1.f - mr));
    }
}

// ---------------- host ----------------

extern "C" void kernel_launch(void* const* d_in, const int* in_sizes, int n_in,
                              void* d_out, int out_size, void* d_ws, size_t ws_size,
                              hipStream_t stream) {
    const float* input = (const float*)d_in[0];
    const int*   ei    = (const int*)d_in[1];
    const float* ew    = (const float*)d_in[2];
    const float* mixw  = (const float*)d_in[3];
    const float* hw    = (const float*)d_in[4];
    const float* hb    = (const float*)d_in[5];
    const float* mw_   = (const float*)d_in[6];
    const float* mb    = (const float*)d_in[7];
    const float* lw    = (const float*)d_in[8];
    const float* lb    = (const float*)d_in[9];
    float* out = (float*)d_out;

    const int* src = ei;
    const int* dst = ei + NE;

    char* ws = (char*)d_ws;
    size_t off = 0;
    auto alloc = [&](size_t bytes) -> void* {
        void* p = ws + off;
        off += (bytes + 255) & ~(size_t)255;
        return p;
    };
    int*   deg      = (int*)alloc((size_t)NN * 4);
    int*   offsets8 = (int*)alloc((size_t)(NN + 1) * 4);
    int*   chunkSum8= (int*)alloc((size_t)NCH * 4);
    int*   chunkOff8= (int*)alloc((size_t)(NCH + 1) * 4);
    int*   binSum   = (int*)alloc((size_t)NCH * 4);
    int*   histT    = (int*)alloc((size_t)NHT * 4);
    int2*  bkt      = (int2*)alloc(((size_t)NE + 8 * NN) * 8);
    int2*  pedge    = (int2*)alloc(((size_t)NE + 8 * NN) * 8);
    unsigned short* Wht  = (unsigned short*)alloc((size_t)256 * 256 * 2);
    unsigned short* Wmlt = (unsigned short*)alloc((size_t)128 * 256 * 2);
    unsigned short* support  = (unsigned short*)alloc((size_t)NN * KD * 2);  // bf16 (MLP path)
    signed char*    supq     = (signed char*)alloc((size_t)NN * KD);        // int8 (gather)
    unsigned short* hidden_g = (unsigned short*)alloc((size_t)NN * KD * 2);  // bf16
    signed char*    gcnq     = (signed char*)alloc((size_t)NN * 128);       // int8 (gather)
    unsigned short* mlp      = (unsigned short*)alloc((size_t)NN * 128 * 2); // bf16

    hipMemsetAsync(deg, 0, (size_t)NN * 4, stream);

    k_hist<<<NBLK, 256, 0, stream>>>(dst, histT, deg);
    k_chunk_sum8<<<NCH, 256, 0, stream>>>(deg, chunkSum8);
    k_scan_chunks<<<1, 256, 0, stream>>>(chunkSum8, chunkOff8);
    k_scan_write8<<<NCH, 256, 0, stream>>>(deg, chunkOff8, offsets8);
    k_scanbins<<<NCH, 256, 0, stream>>>(histT, binSum);
    k_bucketw<<<NBLK, 256, 0, stream>>>(src, dst, ew, histT, chunkOff8, bkt);
    k_place2<<<NCH, 256, 0, stream>>>(bkt, chunkOff8, binSum, offsets8, pedge);

    k_convW<<<256, 256, 0, stream>>>(hw, mw_, lw, Wht, Wmlt);

    int mblk = (NN + 63) / 64;   // 782
    // GEMM1: support(bf16) + supq(int8) = bf16(input) @ hw   (N=256 -> y=2)
    k_gemm<0, 2><<<dim3(mblk, 2), 256, 0, stream>>>(input, Wht, hb, mb, lb, support, supq);
    // SpMM1 (int8 gather) + bias + relu -> hidden_g (bf16)
    k_spmm1<<<NN / 4, 256, 0, stream>>>(offsets8, pedge, (const unsigned*)supq, hb, hidden_g);
    // GEMM2 (GCN): gcnq(int8) = hidden_g @ [mw|lw]   (N=128 -> y=1)
    k_gemm<1, 3><<<dim3(mblk, 1), 256, 0, stream>>>(hidden_g, Wmlt, hb, mb, lb, gcnq, nullptr);
    // GEMM2 (MLP): mlp(bf16) = relu(support+hb) @ [mw|lw] + [mb|lb]
    k_gemm<2, 4><<<dim3(mblk, 1), 256, 0, stream>>>(support, Wmlt, hb, mb, lb, mlp, nullptr);
    // SpMM2 (int8 gather) + mixture combine with mlp -> d_out (write-once)
    k_spmm2<<<NN / 4, 256, 0, stream>>>(offsets8, pedge, (const unsigned short*)gcnq, mlp, mixw, out);
}

// Round 13
// 165.984 us; speedup vs baseline: 1.3698x; 1.1823x over previous
//
#include <hip/hip_runtime.h>
#include <math.h>

#define NN 50000
#define NE 800000
#define KD 256
#define OD 64
#define NCH ((NN + 255) / 256)   // 196 buckets/chunks of 256 nodes
#define EPB 4096                 // edges per histogram/bucket block
#define NBLK ((NE + EPB - 1) / EPB)   // 196 blocks
#define NHT (NCH * NBLK)         // histogram matrix entries (bin-major)

#define QS 32.0f      // int8 quant scale (fixed, power of 2)
#define IQS (1.0f / 32.0f)

using bf16x8 = __attribute__((ext_vector_type(8))) short;
using f32x4  = __attribute__((ext_vector_type(4))) float;

__device__ __forceinline__ unsigned short f2b(float x) {
    union { float f; unsigned u; } c; c.f = x;
    unsigned r = (c.u + 0x7FFF + ((c.u >> 16) & 1)) >> 16;
    return (unsigned short)r;
}
__device__ __forceinline__ float b2f(unsigned short b) {
    union { unsigned u; float f; } c; c.u = ((unsigned)b) << 16;
    return c.f;
}
__device__ __forceinline__ signed char quant8(float v) {
    int q = __float2int_rn(v * QS);
    q = q > 127 ? 127 : (q < -127 ? -127 : q);
    return (signed char)q;
}

// ---------------- CSR build (counting-sort, padded-to-8 segments, LDS-atomic only) --------

// pass A: per-block bucket histogram (LDS atomics ONLY — no global deg atomics)
__global__ __launch_bounds__(256) void k_hist(const int* __restrict__ dst,
                                              int* __restrict__ histT) {
    __shared__ int bins[NCH];
    int t = threadIdx.x, blk = blockIdx.x;
    if (t < NCH) bins[t] = 0;
    __syncthreads();
    int base = blk * EPB;
    #pragma unroll
    for (int i = 0; i < EPB / 256; ++i) {
        int e = base + i * 256 + t;
        if (e < NE) atomicAdd(&bins[dst[e] >> 8], 1);
    }
    __syncthreads();
    if (t < NCH) histT[t * NBLK + blk] = bins[t];   // bin-major
}

// per-bin exclusive scan over its 196 block-counts (0-based) + row total
__global__ __launch_bounds__(256) void k_scanbins(int* __restrict__ histT,
                                                  int* __restrict__ binSum) {
    __shared__ int s[256];
    int bin = blockIdx.x, t = threadIdx.x;
    int v = (t < NBLK) ? histT[bin * NBLK + t] : 0;
    s[t] = v;
    __syncthreads();
    for (int o = 1; o < 256; o <<= 1) {
        int x = (t >= o) ? s[t - o] : 0;
        __syncthreads();
        s[t] += x;
        __syncthreads();
    }
    if (t < NBLK) histT[bin * NBLK + t] = s[t] - v;
    if (t == NBLK - 1) binSum[bin] = s[t];
}

// exclusive scan of bucket totals -> bucket bases in the (unpadded) sorted array
__global__ void k_binscan(const int* __restrict__ binSum, int* __restrict__ binPrefix) {
    __shared__ int s[256];
    int t = threadIdx.x;
    int v = (t < NCH) ? binSum[t] : 0;
    s[t] = v;
    __syncthreads();
    for (int o = 1; o < 256; o <<= 1) {
        int x = (t >= o) ? s[t - o] : 0;
        __syncthreads();
        s[t] += x;
        __syncthreads();
    }
    if (t < NCH) binPrefix[t] = s[t] - v;
    if (t == NCH - 1) binPrefix[NCH] = s[t];
}

// pass C: write edges into bucket-sorted order (0-based positions).
// entry packs (dst<<16)|src (both < 65536) + weight bits -> 8B.
__global__ __launch_bounds__(256) void k_bucketw(const int* __restrict__ src,
                                                 const int* __restrict__ dst,
                                                 const float* __restrict__ w,
                                                 const int* __restrict__ histT,
                                                 const int* __restrict__ binPrefix,
                                                 int2* __restrict__ bkt) {
    __shared__ int cur[NCH];
    int t = threadIdx.x, blk = blockIdx.x;
    if (t < NCH) cur[t] = histT[t * NBLK + blk] + binPrefix[t];
    __syncthreads();
    int base = blk * EPB;
    #pragma unroll
    for (int i = 0; i < EPB / 256; ++i) {
        int e = base + i * 256 + t;
        if (e < NE) {
            int d = dst[e];
            int p = atomicAdd(&cur[d >> 8], 1);
            bkt[p] = make_int2((d << 16) | src[e], __float_as_int(w[e]));
        }
    }
}

// pass C2: per-bucket node degrees from the sorted array (LDS atomics, coalesced reads)
// also writes per-bucket padded sum. Replaces 800k global deg atomics.
__global__ __launch_bounds__(256) void k_deg2(const int2* __restrict__ bkt,
                                              const int* __restrict__ binPrefix,
                                              int* __restrict__ deg,
                                              int* __restrict__ chunkSum8) {
    __shared__ int cnt[256];
    __shared__ int s[256];
    int t = threadIdx.x, b = blockIdx.x;
    cnt[t] = 0;
    __syncthreads();
    int e0 = binPrefix[b], e1 = binPrefix[b + 1];
    for (int e = e0 + t; e < e1; e += 256)
        atomicAdd(&cnt[(((unsigned)bkt[e].x) >> 16) & 255], 1);
    __syncthreads();
    int node = b * 256 + t;
    int c = cnt[t];
    if (node < NN) deg[node] = c;
    s[t] = (node < NN) ? ((c + 7) & ~7) : 0;
    __syncthreads();
    for (int o = 128; o > 0; o >>= 1) {
        if (t < o) s[t] += s[t + o];
        __syncthreads();
    }
    if (t == 0) chunkSum8[b] = s[0];
}

__global__ void k_scan_chunks(const int* __restrict__ chunkSum8, int* __restrict__ chunkOff8) {
    __shared__ int s[256];
    int t = threadIdx.x;
    int v = (t < NCH) ? chunkSum8[t] : 0;
    s[t] = v;
    __syncthreads();
    for (int o = 1; o < 256; o <<= 1) {
        int x = (t >= o) ? s[t - o] : 0;
        __syncthreads();
        s[t] += x;
        __syncthreads();
    }
    if (t < NCH) chunkOff8[t] = s[t] - v;
    if (t == NCH - 1) chunkOff8[NCH] = s[t];   // sentinel = padded total
}

__global__ void k_scan_write8(const int* __restrict__ deg, const int* __restrict__ chunkOff8,
                              int* __restrict__ offsets8) {
    __shared__ int s[256];
    int b = blockIdx.x, t = threadIdx.x;
    int g = b * 256 + t;
    int v = (g < NN) ? ((deg[g] + 7) & ~7) : 0;
    s[t] = v;
    __syncthreads();
    for (int o = 1; o < 256; o <<= 1) {
        int x = (t >= o) ? s[t - o] : 0;
        __syncthreads();
        s[t] += x;
        __syncthreads();
    }
    int excl = s[t] - v + chunkOff8[b];
    if (g <= NN) offsets8[g] = excl;
}

// pass D: within-bucket -> per-node padded-CSR order + pad-fill (fused)
__global__ __launch_bounds__(256) void k_place2(const int2* __restrict__ bkt,
                                                const int* __restrict__ binPrefix,
                                                const int* __restrict__ offsets8,
                                                int2* __restrict__ pedge) {
    __shared__ int ncur[256];
    int t = threadIdx.x, b = blockIdx.x;
    int node = b * 256 + t;
    ncur[t] = (node < NN) ? offsets8[node] : 0;
    __syncthreads();
    int e0 = binPrefix[b], e1 = binPrefix[b + 1];
    for (int e = e0 + t; e < e1; e += 256) {
        int2 v = bkt[e];
        int d = ((unsigned)v.x) >> 16;
        int p = atomicAdd(&ncur[d & 255], 1);
        pedge[p] = v;
    }
    __syncthreads();
    if (node < NN) {
        int p0 = ncur[t];
        int p1 = offsets8[node + 1];
        for (int p = p0; p < p1; ++p) pedge[p] = make_int2(0, 0);
    }
}

// ---------------- weight transpose + bf16 convert (one-time, tiny) ----------------

__global__ void k_convW(const float* __restrict__ hw, const float* __restrict__ mw_,
                        const float* __restrict__ lw,
                        unsigned short* __restrict__ Wht, unsigned short* __restrict__ Wmlt) {
    int idx = blockIdx.x * 256 + threadIdx.x;
    if (idx < 256 * 256) {
        int n = idx >> 8, k = idx & 255;
        Wht[(size_t)n * 256 + k] = f2b(hw[(size_t)k * 256 + n]);
    }
    if (idx < 128 * 256) {
        int n = idx >> 8, k = idx & 255;
        float v = (n < 64) ? mw_[(size_t)k * 64 + n] : lw[(size_t)k * 64 + (n - 64)];
        Wmlt[(size_t)n * 256 + k] = f2b(v);
    }
}

// ---------------- MFMA GEMM: 64x128 block tile, 4 waves, wave-tile 32x64 ----------------
// AM: 0 = A f32 (convert on the fly); 1 = A bf16; 2 = A bf16 + hbias + relu
// EM: 2 = bf16 (ld 256) to Outp AND int8 (ld 256) to Outp2        [gemm1]
//     3 = int8 only (ld 128) to Outp                              [gemm2 GCN]
//     4 = bf16 + region bias (ld 128) to Outp                     [gemm2 MLP]

template <int AM, int EM>
__global__ __launch_bounds__(256) void k_gemm(const void* __restrict__ Ap,
                                              const unsigned short* __restrict__ Bt,
                                              const float* __restrict__ hbias,
                                              const float* __restrict__ mbias,
                                              const float* __restrict__ lbias,
                                              void* __restrict__ Outp,
                                              void* __restrict__ Outp2) {
    __shared__ unsigned short As[64 * 64];
    __shared__ unsigned short Bs[128 * 64];
    const int tid = threadIdx.x;
    const int row0 = blockIdx.x * 64;
    const int n0 = blockIdx.y * 128;
    const int lane = tid & 63;
    const int w = tid >> 6, wm = w >> 1, wn = w & 1;
    const int lr = lane & 15, lg = lane >> 4;
    const int rA = tid >> 2;      // A staging row 0..63
    const int qA = tid & 3;       // A k-quarter (16 bf16)
    const int rB = tid >> 1;      // B staging row 0..127
    const int hB = tid & 1;       // B k-half (32 bf16)

    f32x4 acc[2][4] = {};

    for (int k0 = 0; k0 < KD; k0 += 64) {
        // ---- stage A (64 rows x 64 k bf16, XOR-swizzled 16B slots) ----
        {
            int gr = row0 + rA;
            unsigned short tmp[16];
            if (AM == 0) {
                const float* A = (const float*)Ap;
                if (gr < NN) {
                    #pragma unroll
                    for (int i = 0; i < 4; ++i) {
                        float4 v = *reinterpret_cast<const float4*>(
                            &A[(size_t)gr * KD + k0 + qA * 16 + i * 4]);
                        tmp[i * 4 + 0] = f2b(v.x); tmp[i * 4 + 1] = f2b(v.y);
                        tmp[i * 4 + 2] = f2b(v.z); tmp[i * 4 + 3] = f2b(v.w);
                    }
                } else {
                    #pragma unroll
                    for (int i = 0; i < 16; ++i) tmp[i] = 0;
                }
            } else {
                const unsigned short* A = (const unsigned short*)Ap;
                if (gr < NN) {
                    *reinterpret_cast<uint4*>(&tmp[0]) =
                        *reinterpret_cast<const uint4*>(&A[(size_t)gr * KD + k0 + qA * 16]);
                    *reinterpret_cast<uint4*>(&tmp[8]) =
                        *reinterpret_cast<const uint4*>(&A[(size_t)gr * KD + k0 + qA * 16 + 8]);
                    if (AM == 2) {
                        #pragma unroll
                        for (int i = 0; i < 4; ++i) {
                            float4 hb4 = *reinterpret_cast<const float4*>(&hbias[k0 + qA * 16 + i * 4]);
                            tmp[i * 4 + 0] = f2b(fmaxf(b2f(tmp[i * 4 + 0]) + hb4.x, 0.f));
                            tmp[i * 4 + 1] = f2b(fmaxf(b2f(tmp[i * 4 + 1]) + hb4.y, 0.f));
                            tmp[i * 4 + 2] = f2b(fmaxf(b2f(tmp[i * 4 + 2]) + hb4.z, 0.f));
                            tmp[i * 4 + 3] = f2b(fmaxf(b2f(tmp[i * 4 + 3]) + hb4.w, 0.f));
                        }
                    }
                } else {
                    #pragma unroll
                    for (int i = 0; i < 16; ++i) tmp[i] = 0;
                }
            }
            int s0 = (qA * 2) ^ (rA & 7);
            int s1 = (qA * 2 + 1) ^ (rA & 7);
            *reinterpret_cast<uint4*>(&As[rA * 64 + s0 * 8]) = *reinterpret_cast<const uint4*>(&tmp[0]);
            *reinterpret_cast<uint4*>(&As[rA * 64 + s1 * 8]) = *reinterpret_cast<const uint4*>(&tmp[8]);
        }
        // ---- stage B (128 rows x 64 k; Bt is [N][K] bf16 row-major) ----
        {
            const unsigned short* B = Bt + (size_t)(n0 + rB) * KD + k0 + hB * 32;
            #pragma unroll
            for (int i = 0; i < 4; ++i) {
                uint4 u = *reinterpret_cast<const uint4*>(B + i * 8);
                int slot = (hB * 4 + i) ^ (rB & 7);
                *reinterpret_cast<uint4*>(&Bs[rB * 64 + slot * 8]) = u;
            }
        }
        __syncthreads();
        // ---- MFMA: wave 32x64, fragments 2x4, 2 K-slices of 32 ----
        #pragma unroll
        for (int ks = 0; ks < 2; ++ks) {
            int slot = ks * 4 + lg;
            bf16x8 a[2], b[4];
            #pragma unroll
            for (int fm = 0; fm < 2; ++fm) {
                int ra = wm * 32 + fm * 16 + lr;
                a[fm] = *reinterpret_cast<const bf16x8*>(&As[ra * 64 + ((slot ^ (ra & 7))) * 8]);
            }
            #pragma unroll
            for (int fn = 0; fn < 4; ++fn) {
                int rb = wn * 64 + fn * 16 + lr;
                b[fn] = *reinterpret_cast<const bf16x8*>(&Bs[rb * 64 + ((slot ^ (rb & 7))) * 8]);
            }
            #pragma unroll
            for (int fm = 0; fm < 2; ++fm)
                #pragma unroll
                for (int fn = 0; fn < 4; ++fn)
                    acc[fm][fn] = __builtin_amdgcn_mfma_f32_16x16x32_bf16(a[fm], b[fn], acc[fm][fn], 0, 0, 0);
        }
        __syncthreads();
    }
    // ---- epilogue: C/D col=lane&15, row=(lane>>4)*4+reg ----
    #pragma unroll
    for (int fm = 0; fm < 2; ++fm) {
        #pragma unroll
        for (int j = 0; j < 4; ++j) {
            int grow = row0 + wm * 32 + fm * 16 + lg * 4 + j;
            if (grow >= NN) continue;
            #pragma unroll
            for (int fn = 0; fn < 4; ++fn) {
                int gcol = n0 + wn * 64 + fn * 16 + lr;
                float v = acc[fm][fn][j];
                if (EM == 2) {
                    ((unsigned short*)Outp)[(size_t)grow * 256 + gcol] = f2b(v);
                    ((signed char*)Outp2)[(size_t)grow * 256 + gcol] = quant8(v);
                } else if (EM == 3) {
                    ((signed char*)Outp)[(size_t)grow * 128 + gcol] = quant8(v);
                } else {  // EM == 4
                    float b = (gcol < 64) ? mbias[gcol] : lbias[gcol - 64];
                    ((unsigned short*)Outp)[(size_t)grow * 128 + gcol] = f2b(v + b);
                }
            }
        }
    }
}

// ---------------- SpMM1 (int8 gather) + bias + relu -> hidden_g bf16 ----------------

__global__ __launch_bounds__(256) void k_spmm1(const int* __restrict__ off8,
                                               const int2* __restrict__ pedge,
                                               const unsigned* __restrict__ supq,   // [NN][64] u32 (4 int8)
                                               const float* __restrict__ bias,
                                               unsigned short* __restrict__ hg) {
    int lane = threadIdx.x & 63;
    int d = blockIdx.x * 4 + (threadIdx.x >> 6);
    int e0 = off8[d], e1 = off8[d + 1];
    float a0 = 0.f, a1 = 0.f, a2 = 0.f, a3 = 0.f;
    for (int e = e0; e < e1; e += 8) {
        int2 E[8];
        unsigned U[8];
        #pragma unroll
        for (int i = 0; i < 8; ++i) E[i] = pedge[e + i];
        #pragma unroll
        for (int i = 0; i < 8; ++i) U[i] = supq[(size_t)(E[i].x & 0xffff) * 64 + lane];
        #pragma unroll
        for (int i = 0; i < 8; ++i) {
            float w = __int_as_float(E[i].y);
            unsigned u = U[i];
            a0 = fmaf(w, (float)((int)(signed char)(u)), a0);
            a1 = fmaf(w, (float)((int)(signed char)(u >> 8)), a1);
            a2 = fmaf(w, (float)((int)(signed char)(u >> 16)), a2);
            a3 = fmaf(w, (float)((int)(signed char)(u >> 24)), a3);
        }
    }
    float4 b = *reinterpret_cast<const float4*>(&bias[lane * 4]);
    ushort4 o;
    o.x = f2b(fmaxf(a0 * IQS + b.x, 0.f));
    o.y = f2b(fmaxf(a1 * IQS + b.y, 0.f));
    o.z = f2b(fmaxf(a2 * IQS + b.z, 0.f));
    o.w = f2b(fmaxf(a3 * IQS + b.w, 0.f));
    reinterpret_cast<ushort4*>(hg)[(size_t)d * 64 + lane] = o;
}

// ---------------- SpMM2 (int8 gather, 128 dims) + mixture with mlp (write-once) ----------------

__global__ __launch_bounds__(256) void k_spmm2(const int* __restrict__ off8,
                                               const int2* __restrict__ pedge,
                                               const unsigned short* __restrict__ gq,  // [NN][64] u16 (2 int8)
                                               const unsigned short* __restrict__ mlp, // [NN][128] bf16
                                               const float* __restrict__ mixw,
                                               float* __restrict__ out) {
    int lane = threadIdx.x & 63;
    int d = blockIdx.x * 4 + (threadIdx.x >> 6);
    int e0 = off8[d], e1 = off8[d + 1];
    float a0 = 0.f, a1 = 0.f;
    for (int e = e0; e < e1; e += 8) {
        int2 E[8];
        unsigned short U[8];
        #pragma unroll
        for (int i = 0; i < 8; ++i) E[i] = pedge[e + i];
        #pragma unroll
        for (int i = 0; i < 8; ++i) U[i] = gq[(size_t)(E[i].x & 0xffff) * 64 + lane];
        #pragma unroll
        for (int i = 0; i < 8; ++i) {
            float w = __int_as_float(E[i].y);
            a0 = fmaf(w, (float)((int)(signed char)(U[i] & 0xff)), a0);
            a1 = fmaf(w, (float)((int)(signed char)(U[i] >> 8)), a1);
        }
    }
    float g0 = a0 * IQS, g1 = a1 * IQS;
    ushort2 mu = reinterpret_cast<const ushort2*>(mlp)[(size_t)d * 64 + lane];
    float m0 = b2f(mu.x), m1 = b2f(mu.y);
    float mw = mixw[0];
    float mr = 1.f / (1.f + expf(-mw));
    int c = lane * 2;
    if (c < 64) {
        *reinterpret_cast<float2*>(out + (size_t)d * OD + c) =
            make_float2(g0 * mw + m0 * (1.f - mw), g1 * mw + m1 * (1.f - mw));
    } else {
        *reinterpret_cast<float2*>(out + (size_t)NN * OD + (size_t)d * OD + (c - 64)) =
            make_float2(g0 * mr + m0 * (1.f - mr), g1 * mr + m1 * (1.f - mr));
    }
}

// ---------------- host ----------------

extern "C" void kernel_launch(void* const* d_in, const int* in_sizes, int n_in,
                              void* d_out, int out_size, void* d_ws, size_t ws_size,
                              hipStream_t stream) {
    const float* input = (const float*)d_in[0];
    const int*   ei    = (const int*)d_in[1];
    const float* ew    = (const float*)d_in[2];
    const float* mixw  = (const float*)d_in[3];
    const float* hw    = (const float*)d_in[4];
    const float* hb    = (const float*)d_in[5];
    const float* mw_   = (const float*)d_in[6];
    const float* mb    = (const float*)d_in[7];
    const float* lw    = (const float*)d_in[8];
    const float* lb    = (const float*)d_in[9];
    float* out = (float*)d_out;

    const int* src = ei;
    const int* dst = ei + NE;

    char* ws = (char*)d_ws;
    size_t off = 0;
    auto alloc = [&](size_t bytes) -> void* {
        void* p = ws + off;
        off += (bytes + 255) & ~(size_t)255;
        return p;
    };
    int*   deg      = (int*)alloc((size_t)NN * 4);
    int*   offsets8 = (int*)alloc((size_t)(NN + 1) * 4);
    int*   chunkSum8= (int*)alloc((size_t)NCH * 4);
    int*   chunkOff8= (int*)alloc((size_t)(NCH + 1) * 4);
    int*   binSum   = (int*)alloc((size_t)NCH * 4);
    int*   binPrefix= (int*)alloc((size_t)(NCH + 1) * 4);
    int*   histT    = (int*)alloc((size_t)NHT * 4);
    int2*  bkt      = (int2*)alloc((size_t)NE * 8);
    int2*  pedge    = (int2*)alloc(((size_t)NE + 8 * NN) * 8);
    unsigned short* Wht  = (unsigned short*)alloc((size_t)256 * 256 * 2);
    unsigned short* Wmlt = (unsigned short*)alloc((size_t)128 * 256 * 2);
    unsigned short* support  = (unsigned short*)alloc((size_t)NN * KD * 2);  // bf16 (MLP path)
    signed char*    supq     = (signed char*)alloc((size_t)NN * KD);        // int8 (gather)
    unsigned short* hidden_g = (unsigned short*)alloc((size_t)NN * KD * 2);  // bf16
    signed char*    gcnq     = (signed char*)alloc((size_t)NN * 128);       // int8 (gather)
    unsigned short* mlp      = (unsigned short*)alloc((size_t)NN * 128 * 2); // bf16

    k_hist<<<NBLK, 256, 0, stream>>>(dst, histT);
    k_scanbins<<<NCH, 256, 0, stream>>>(histT, binSum);
    k_binscan<<<1, 256, 0, stream>>>(binSum, binPrefix);
    k_bucketw<<<NBLK, 256, 0, stream>>>(src, dst, ew, histT, binPrefix, bkt);
    k_deg2<<<NCH, 256, 0, stream>>>(bkt, binPrefix, deg, chunkSum8);
    k_scan_chunks<<<1, 256, 0, stream>>>(chunkSum8, chunkOff8);
    k_scan_write8<<<NCH, 256, 0, stream>>>(deg, chunkOff8, offsets8);
    k_place2<<<NCH, 256, 0, stream>>>(bkt, binPrefix, offsets8, pedge);

    k_convW<<<256, 256, 0, stream>>>(hw, mw_, lw, Wht, Wmlt);

    int mblk = (NN + 63) / 64;   // 782
    // GEMM1: support(bf16) + supq(int8) = bf16(input) @ hw   (N=256 -> y=2)
    k_gemm<0, 2><<<dim3(mblk, 2), 256, 0, stream>>>(input, Wht, hb, mb, lb, support, supq);
    // SpMM1 (int8 gather) + bias + relu -> hidden_g (bf16)
    k_spmm1<<<NN / 4, 256, 0, stream>>>(offsets8, pedge, (const unsigned*)supq, hb, hidden_g);
    // GEMM2 (GCN): gcnq(int8) = hidden_g @ [mw|lw]   (N=128 -> y=1)
    k_gemm<1, 3><<<dim3(mblk, 1), 256, 0, stream>>>(hidden_g, Wmlt, hb, mb, lb, gcnq, nullptr);
    // GEMM2 (MLP): mlp(bf16) = relu(support+hb) @ [mw|lw] + [mb|lb]
    k_gemm<2, 4><<<dim3(mblk, 1), 256, 0, stream>>>(support, Wmlt, hb, mb, lb, mlp, nullptr);
    // SpMM2 (int8 gather) + mixture combine with mlp -> d_out (write-once)
    k_spmm2<<<NN / 4, 256, 0, stream>>>(offsets8, pedge, (const unsigned short*)gcnq, mlp, mixw, out);
}

// Round 14
// 158.435 us; speedup vs baseline: 1.4351x; 1.0476x over previous
//
#include <hip/hip_runtime.h>
#include <math.h>

#define NN 50000
#define NE 800000
#define KD 256
#define OD 64
#define NCH ((NN + 255) / 256)   // 196 buckets/chunks of 256 nodes
#define EPB 4096                 // edges per histogram/bucket block
#define NBLK ((NE + EPB - 1) / EPB)   // 196 blocks
#define NHT (NCH * NBLK)         // histogram matrix entries (bin-major)

#define QS 32.0f      // int8 quant scale for support/gcn_pre
#define IQS (1.0f / 32.0f)
#define QS2 16.0f     // int8 quant scale for hidden (range +-7.94)
#define IQS2 (1.0f / 16.0f)

using bf16x8 = __attribute__((ext_vector_type(8))) short;
using f32x4  = __attribute__((ext_vector_type(4))) float;

__device__ __forceinline__ unsigned short f2b(float x) {
    union { float f; unsigned u; } c; c.f = x;
    unsigned r = (c.u + 0x7FFF + ((c.u >> 16) & 1)) >> 16;
    return (unsigned short)r;
}
__device__ __forceinline__ float b2f(unsigned short b) {
    union { unsigned u; float f; } c; c.u = ((unsigned)b) << 16;
    return c.f;
}
__device__ __forceinline__ signed char quant8(float v) {
    int q = __float2int_rn(v * QS);
    q = q > 127 ? 127 : (q < -127 ? -127 : q);
    return (signed char)q;
}
__device__ __forceinline__ unsigned quant16u(float v) {   // v >= 0 (post-relu), scale 16
    int q = __float2int_rn(v * QS2);
    return (unsigned)(q > 127 ? 127 : q);
}

// ---------------- CSR build (counting-sort, padded-to-8 segments, LDS-atomic only) --------

__global__ __launch_bounds__(256) void k_hist(const int* __restrict__ dst,
                                              int* __restrict__ histT) {
    __shared__ int bins[NCH];
    int t = threadIdx.x, blk = blockIdx.x;
    if (t < NCH) bins[t] = 0;
    __syncthreads();
    int base = blk * EPB;
    #pragma unroll
    for (int i = 0; i < EPB / 256; ++i) {
        int e = base + i * 256 + t;
        if (e < NE) atomicAdd(&bins[dst[e] >> 8], 1);
    }
    __syncthreads();
    if (t < NCH) histT[t * NBLK + blk] = bins[t];   // bin-major
}

__global__ __launch_bounds__(256) void k_scanbins(int* __restrict__ histT,
                                                  int* __restrict__ binSum) {
    __shared__ int s[256];
    int bin = blockIdx.x, t = threadIdx.x;
    int v = (t < NBLK) ? histT[bin * NBLK + t] : 0;
    s[t] = v;
    __syncthreads();
    for (int o = 1; o < 256; o <<= 1) {
        int x = (t >= o) ? s[t - o] : 0;
        __syncthreads();
        s[t] += x;
        __syncthreads();
    }
    if (t < NBLK) histT[bin * NBLK + t] = s[t] - v;
    if (t == NBLK - 1) binSum[bin] = s[t];
}

__global__ void k_binscan(const int* __restrict__ binSum, int* __restrict__ binPrefix) {
    __shared__ int s[256];
    int t = threadIdx.x;
    int v = (t < NCH) ? binSum[t] : 0;
    s[t] = v;
    __syncthreads();
    for (int o = 1; o < 256; o <<= 1) {
        int x = (t >= o) ? s[t - o] : 0;
        __syncthreads();
        s[t] += x;
        __syncthreads();
    }
    if (t < NCH) binPrefix[t] = s[t] - v;
    if (t == NCH - 1) binPrefix[NCH] = s[t];
}

__global__ __launch_bounds__(256) void k_bucketw(const int* __restrict__ src,
                                                 const int* __restrict__ dst,
                                                 const float* __restrict__ w,
                                                 const int* __restrict__ histT,
                                                 const int* __restrict__ binPrefix,
                                                 int2* __restrict__ bkt) {
    __shared__ int cur[NCH];
    int t = threadIdx.x, blk = blockIdx.x;
    if (t < NCH) cur[t] = histT[t * NBLK + blk] + binPrefix[t];
    __syncthreads();
    int base = blk * EPB;
    #pragma unroll
    for (int i = 0; i < EPB / 256; ++i) {
        int e = base + i * 256 + t;
        if (e < NE) {
            int d = dst[e];
            int p = atomicAdd(&cur[d >> 8], 1);
            bkt[p] = make_int2((d << 16) | src[e], __float_as_int(w[e]));
        }
    }
}

// per-bucket node degrees from the sorted array (LDS atomics, coalesced reads)
__global__ __launch_bounds__(256) void k_deg2(const int2* __restrict__ bkt,
                                              const int* __restrict__ binPrefix,
                                              int* __restrict__ deg,
                                              int* __restrict__ chunkSum8) {
    __shared__ int cnt[256];
    __shared__ int s[256];
    int t = threadIdx.x, b = blockIdx.x;
    cnt[t] = 0;
    __syncthreads();
    int e0 = binPrefix[b], e1 = binPrefix[b + 1];
    for (int e = e0 + t; e < e1; e += 256)
        atomicAdd(&cnt[(((unsigned)bkt[e].x) >> 16) & 255], 1);
    __syncthreads();
    int node = b * 256 + t;
    int c = cnt[t];
    if (node < NN) deg[node] = c;
    s[t] = (node < NN) ? ((c + 7) & ~7) : 0;
    __syncthreads();
    for (int o = 128; o > 0; o >>= 1) {
        if (t < o) s[t] += s[t + o];
        __syncthreads();
    }
    if (t == 0) chunkSum8[b] = s[0];
}

__global__ void k_scan_chunks(const int* __restrict__ chunkSum8, int* __restrict__ chunkOff8) {
    __shared__ int s[256];
    int t = threadIdx.x;
    int v = (t < NCH) ? chunkSum8[t] : 0;
    s[t] = v;
    __syncthreads();
    for (int o = 1; o < 256; o <<= 1) {
        int x = (t >= o) ? s[t - o] : 0;
        __syncthreads();
        s[t] += x;
        __syncthreads();
    }
    if (t < NCH) chunkOff8[t] = s[t] - v;
    if (t == NCH - 1) chunkOff8[NCH] = s[t];   // sentinel = padded total
}

// fused: compute per-node padded offsets (from deg, in LDS) + write offsets8 +
// place bucket-sorted edges into per-node padded-CSR order + pad-fill
__global__ __launch_bounds__(256) void k_place2f(const int2* __restrict__ bkt,
                                                 const int* __restrict__ binPrefix,
                                                 const int* __restrict__ chunkOff8,
                                                 const int* __restrict__ deg,
                                                 int* __restrict__ offsets8,
                                                 int2* __restrict__ pedge) {
    __shared__ int s[256];
    __shared__ int ncur[256];
    int t = threadIdx.x, b = blockIdx.x;
    int node = b * 256 + t;
    int dv = (node < NN) ? deg[node] : 0;
    int pv = (dv + 7) & ~7;
    s[t] = pv;
    __syncthreads();
    for (int o = 1; o < 256; o <<= 1) {
        int x = (t >= o) ? s[t - o] : 0;
        __syncthreads();
        s[t] += x;
        __syncthreads();
    }
    int excl = s[t] - pv + chunkOff8[b];
    if (node <= NN) offsets8[node] = excl;
    ncur[t] = excl;
    __syncthreads();
    int e0 = binPrefix[b], e1 = binPrefix[b + 1];
    for (int e = e0 + t; e < e1; e += 256) {
        int2 v = bkt[e];
        int d = ((unsigned)v.x) >> 16;
        int p = atomicAdd(&ncur[d & 255], 1);
        pedge[p] = v;
    }
    __syncthreads();
    if (node < NN) {
        int p0 = ncur[t];          // = excl + dv
        int p1 = excl + pv;
        for (int p = p0; p < p1; ++p) pedge[p] = make_int2(0, 0);
    }
}

// ---------------- weight transpose + bf16 convert (one-time, tiny) ----------------

__global__ void k_convW(const float* __restrict__ hw, const float* __restrict__ mw_,
                        const float* __restrict__ lw,
                        unsigned short* __restrict__ Wht, unsigned short* __restrict__ Wmlt) {
    int idx = blockIdx.x * 256 + threadIdx.x;
    if (idx < 256 * 256) {
        int n = idx >> 8, k = idx & 255;
        Wht[(size_t)n * 256 + k] = f2b(hw[(size_t)k * 256 + n]);
    }
    if (idx < 128 * 256) {
        int n = idx >> 8, k = idx & 255;
        float v = (n < 64) ? mw_[(size_t)k * 64 + n] : lw[(size_t)k * 64 + (n - 64)];
        Wmlt[(size_t)n * 256 + k] = f2b(v);
    }
}

// ---------------- MFMA GEMM: 64x128 block tile, 4 waves, wave-tile 32x64 ----------------
// AM: 0 = A f32 (convert); 2 = A bf16 + hbias + relu; 4 = A int8 dequant (x 1/16)
// EM: 2 = bf16 (ld 256) + int8 (ld 256, QS)   [gemm1]
//     3 = int8 only (ld 128, QS)              [gemm2 GCN]
//     4 = bf16 + region bias (ld 128)         [gemm2 MLP]

template <int AM, int EM>
__global__ __launch_bounds__(256) void k_gemm(const void* __restrict__ Ap,
                                              const unsigned short* __restrict__ Bt,
                                              const float* __restrict__ hbias,
                                              const float* __restrict__ mbias,
                                              const float* __restrict__ lbias,
                                              void* __restrict__ Outp,
                                              void* __restrict__ Outp2) {
    __shared__ unsigned short As[64 * 64];
    __shared__ unsigned short Bs[128 * 64];
    const int tid = threadIdx.x;
    const int row0 = blockIdx.x * 64;
    const int n0 = blockIdx.y * 128;
    const int lane = tid & 63;
    const int w = tid >> 6, wm = w >> 1, wn = w & 1;
    const int lr = lane & 15, lg = lane >> 4;
    const int rA = tid >> 2;      // A staging row 0..63
    const int qA = tid & 3;       // A k-quarter (16 bf16)
    const int rB = tid >> 1;      // B staging row 0..127
    const int hB = tid & 1;       // B k-half (32 bf16)

    f32x4 acc[2][4] = {};

    for (int k0 = 0; k0 < KD; k0 += 64) {
        // ---- stage A (64 rows x 64 k bf16, XOR-swizzled 16B slots) ----
        {
            int gr = row0 + rA;
            unsigned short tmp[16];
            if (AM == 0) {
                const float* A = (const float*)Ap;
                if (gr < NN) {
                    #pragma unroll
                    for (int i = 0; i < 4; ++i) {
                        float4 v = *reinterpret_cast<const float4*>(
                            &A[(size_t)gr * KD + k0 + qA * 16 + i * 4]);
                        tmp[i * 4 + 0] = f2b(v.x); tmp[i * 4 + 1] = f2b(v.y);
                        tmp[i * 4 + 2] = f2b(v.z); tmp[i * 4 + 3] = f2b(v.w);
                    }
                } else {
                    #pragma unroll
                    for (int i = 0; i < 16; ++i) tmp[i] = 0;
                }
            } else if (AM == 2) {
                const unsigned short* A = (const unsigned short*)Ap;
                if (gr < NN) {
                    *reinterpret_cast<uint4*>(&tmp[0]) =
                        *reinterpret_cast<const uint4*>(&A[(size_t)gr * KD + k0 + qA * 16]);
                    *reinterpret_cast<uint4*>(&tmp[8]) =
                        *reinterpret_cast<const uint4*>(&A[(size_t)gr * KD + k0 + qA * 16 + 8]);
                    #pragma unroll
                    for (int i = 0; i < 4; ++i) {
                        float4 hb4 = *reinterpret_cast<const float4*>(&hbias[k0 + qA * 16 + i * 4]);
                        tmp[i * 4 + 0] = f2b(fmaxf(b2f(tmp[i * 4 + 0]) + hb4.x, 0.f));
                        tmp[i * 4 + 1] = f2b(fmaxf(b2f(tmp[i * 4 + 1]) + hb4.y, 0.f));
                        tmp[i * 4 + 2] = f2b(fmaxf(b2f(tmp[i * 4 + 2]) + hb4.z, 0.f));
                        tmp[i * 4 + 3] = f2b(fmaxf(b2f(tmp[i * 4 + 3]) + hb4.w, 0.f));
                    }
                } else {
                    #pragma unroll
                    for (int i = 0; i < 16; ++i) tmp[i] = 0;
                }
            } else {  // AM == 4: int8 A, dequant x 1/16 (exact in bf16)
                const signed char* A = (const signed char*)Ap;
                if (gr < NN) {
                    signed char q[16];
                    *reinterpret_cast<uint4*>(q) =
                        *reinterpret_cast<const uint4*>(&A[(size_t)gr * KD + k0 + qA * 16]);
                    #pragma unroll
                    for (int i = 0; i < 16; ++i) tmp[i] = f2b((float)q[i] * IQS2);
                } else {
                    #pragma unroll
                    for (int i = 0; i < 16; ++i) tmp[i] = 0;
                }
            }
            int s0 = (qA * 2) ^ (rA & 7);
            int s1 = (qA * 2 + 1) ^ (rA & 7);
            *reinterpret_cast<uint4*>(&As[rA * 64 + s0 * 8]) = *reinterpret_cast<const uint4*>(&tmp[0]);
            *reinterpret_cast<uint4*>(&As[rA * 64 + s1 * 8]) = *reinterpret_cast<const uint4*>(&tmp[8]);
        }
        // ---- stage B (128 rows x 64 k; Bt is [N][K] bf16 row-major) ----
        {
            const unsigned short* B = Bt + (size_t)(n0 + rB) * KD + k0 + hB * 32;
            #pragma unroll
            for (int i = 0; i < 4; ++i) {
                uint4 u = *reinterpret_cast<const uint4*>(B + i * 8);
                int slot = (hB * 4 + i) ^ (rB & 7);
                *reinterpret_cast<uint4*>(&Bs[rB * 64 + slot * 8]) = u;
            }
        }
        __syncthreads();
        // ---- MFMA: wave 32x64, fragments 2x4, 2 K-slices of 32 ----
        #pragma unroll
        for (int ks = 0; ks < 2; ++ks) {
            int slot = ks * 4 + lg;
            bf16x8 a[2], b[4];
            #pragma unroll
            for (int fm = 0; fm < 2; ++fm) {
                int ra = wm * 32 + fm * 16 + lr;
                a[fm] = *reinterpret_cast<const bf16x8*>(&As[ra * 64 + ((slot ^ (ra & 7))) * 8]);
            }
            #pragma unroll
            for (int fn = 0; fn < 4; ++fn) {
                int rb = wn * 64 + fn * 16 + lr;
                b[fn] = *reinterpret_cast<const bf16x8*>(&Bs[rb * 64 + ((slot ^ (rb & 7))) * 8]);
            }
            #pragma unroll
            for (int fm = 0; fm < 2; ++fm)
                #pragma unroll
                for (int fn = 0; fn < 4; ++fn)
                    acc[fm][fn] = __builtin_amdgcn_mfma_f32_16x16x32_bf16(a[fm], b[fn], acc[fm][fn], 0, 0, 0);
        }
        __syncthreads();
    }
    // ---- epilogue: C/D col=lane&15, row=(lane>>4)*4+reg ----
    #pragma unroll
    for (int fm = 0; fm < 2; ++fm) {
        #pragma unroll
        for (int j = 0; j < 4; ++j) {
            int grow = row0 + wm * 32 + fm * 16 + lg * 4 + j;
            if (grow >= NN) continue;
            #pragma unroll
            for (int fn = 0; fn < 4; ++fn) {
                int gcol = n0 + wn * 64 + fn * 16 + lr;
                float v = acc[fm][fn][j];
                if (EM == 2) {
                    ((unsigned short*)Outp)[(size_t)grow * 256 + gcol] = f2b(v);
                    ((signed char*)Outp2)[(size_t)grow * 256 + gcol] = quant8(v);
                } else if (EM == 3) {
                    ((signed char*)Outp)[(size_t)grow * 128 + gcol] = quant8(v);
                } else {  // EM == 4
                    float b = (gcol < 64) ? mbias[gcol] : lbias[gcol - 64];
                    ((unsigned short*)Outp)[(size_t)grow * 128 + gcol] = f2b(v + b);
                }
            }
        }
    }
}

// ---------------- SpMM1 (int8 gather) + bias + relu -> hgq int8 (scale 16) ----------------
// 2 dsts per wave, interleaved streams for 2x memory-level parallelism

__global__ __launch_bounds__(256) void k_spmm1(const int* __restrict__ off8,
                                               const int2* __restrict__ pedge,
                                               const unsigned* __restrict__ supq,   // [NN][64] u32
                                               const float* __restrict__ bias,
                                               unsigned* __restrict__ hgq) {        // [NN][64] u32
    int lane = threadIdx.x & 63;
    int wid = blockIdx.x * 4 + (threadIdx.x >> 6);
    int d0 = wid * 2, d1 = d0 + 1;
    int ea = off8[d0], eA = off8[d0 + 1], eB = off8[d0 + 2];
    int eb = eA;
    float a0 = 0.f, a1 = 0.f, a2 = 0.f, a3 = 0.f;
    float c0 = 0.f, c1 = 0.f, c2 = 0.f, c3 = 0.f;
    for (; ea < eA && eb < eB; ea += 8, eb += 8) {
        int2 Ea[8], Eb[8];
        unsigned Ua[8], Ub[8];
        #pragma unroll
        for (int i = 0; i < 8; ++i) { Ea[i] = pedge[ea + i]; Eb[i] = pedge[eb + i]; }
        #pragma unroll
        for (int i = 0; i < 8; ++i) {
            Ua[i] = supq[(size_t)(Ea[i].x & 0xffff) * 64 + lane];
            Ub[i] = supq[(size_t)(Eb[i].x & 0xffff) * 64 + lane];
        }
        #pragma unroll
        for (int i = 0; i < 8; ++i) {
            float wa = __int_as_float(Ea[i].y), wb = __int_as_float(Eb[i].y);
            unsigned ua = Ua[i], ub = Ub[i];
            a0 = fmaf(wa, (float)((int)(signed char)(ua)), a0);
            a1 = fmaf(wa, (float)((int)(signed char)(ua >> 8)), a1);
            a2 = fmaf(wa, (float)((int)(signed char)(ua >> 16)), a2);
            a3 = fmaf(wa, (float)((int)(signed char)(ua >> 24)), a3);
            c0 = fmaf(wb, (float)((int)(signed char)(ub)), c0);
            c1 = fmaf(wb, (float)((int)(signed char)(ub >> 8)), c1);
            c2 = fmaf(wb, (float)((int)(signed char)(ub >> 16)), c2);
            c3 = fmaf(wb, (float)((int)(signed char)(ub >> 24)), c3);
        }
    }
    for (; ea < eA; ea += 8) {
        int2 E[8]; unsigned U[8];
        #pragma unroll
        for (int i = 0; i < 8; ++i) E[i] = pedge[ea + i];
        #pragma unroll
        for (int i = 0; i < 8; ++i) U[i] = supq[(size_t)(E[i].x & 0xffff) * 64 + lane];
        #pragma unroll
        for (int i = 0; i < 8; ++i) {
            float w = __int_as_float(E[i].y); unsigned u = U[i];
            a0 = fmaf(w, (float)((int)(signed char)(u)), a0);
            a1 = fmaf(w, (float)((int)(signed char)(u >> 8)), a1);
            a2 = fmaf(w, (float)((int)(signed char)(u >> 16)), a2);
            a3 = fmaf(w, (float)((int)(signed char)(u >> 24)), a3);
        }
    }
    for (; eb < eB; eb += 8) {
        int2 E[8]; unsigned U[8];
        #pragma unroll
        for (int i = 0; i < 8; ++i) E[i] = pedge[eb + i];
        #pragma unroll
        for (int i = 0; i < 8; ++i) U[i] = supq[(size_t)(E[i].x & 0xffff) * 64 + lane];
        #pragma unroll
        for (int i = 0; i < 8; ++i) {
            float w = __int_as_float(E[i].y); unsigned u = U[i];
            c0 = fmaf(w, (float)((int)(signed char)(u)), c0);
            c1 = fmaf(w, (float)((int)(signed char)(u >> 8)), c1);
            c2 = fmaf(w, (float)((int)(signed char)(u >> 16)), c2);
            c3 = fmaf(w, (float)((int)(signed char)(u >> 24)), c3);
        }
    }
    float4 b = *reinterpret_cast<const float4*>(&bias[lane * 4]);
    unsigned oa = quant16u(fmaxf(a0 * IQS + b.x, 0.f))
                | (quant16u(fmaxf(a1 * IQS + b.y, 0.f)) << 8)
                | (quant16u(fmaxf(a2 * IQS + b.z, 0.f)) << 16)
                | (quant16u(fmaxf(a3 * IQS + b.w, 0.f)) << 24);
    unsigned oc = quant16u(fmaxf(c0 * IQS + b.x, 0.f))
                | (quant16u(fmaxf(c1 * IQS + b.y, 0.f)) << 8)
                | (quant16u(fmaxf(c2 * IQS + b.z, 0.f)) << 16)
                | (quant16u(fmaxf(c3 * IQS + b.w, 0.f)) << 24);
    hgq[(size_t)d0 * 64 + lane] = oa;
    hgq[(size_t)d1 * 64 + lane] = oc;
}

// ---------------- SpMM2 (int8 gather, 128 dims) + mixture with mlp, 2 dsts/wave ------------

__global__ __launch_bounds__(256) void k_spmm2(const int* __restrict__ off8,
                                               const int2* __restrict__ pedge,
                                               const unsigned short* __restrict__ gq,  // [NN][64] u16
                                               const unsigned short* __restrict__ mlp, // [NN][128] bf16
                                               const float* __restrict__ mixw,
                                               float* __restrict__ out) {
    int lane = threadIdx.x & 63;
    int wid = blockIdx.x * 4 + (threadIdx.x >> 6);
    int d0 = wid * 2, d1 = d0 + 1;
    int ea = off8[d0], eA = off8[d0 + 1], eB = off8[d0 + 2];
    int eb = eA;
    float a0 = 0.f, a1 = 0.f, c0 = 0.f, c1 = 0.f;
    for (; ea < eA && eb < eB; ea += 8, eb += 8) {
        int2 Ea[8], Eb[8];
        unsigned short Ua[8], Ub[8];
        #pragma unroll
        for (int i = 0; i < 8; ++i) { Ea[i] = pedge[ea + i]; Eb[i] = pedge[eb + i]; }
        #pragma unroll
        for (int i = 0; i < 8; ++i) {
            Ua[i] = gq[(size_t)(Ea[i].x & 0xffff) * 64 + lane];
            Ub[i] = gq[(size_t)(Eb[i].x & 0xffff) * 64 + lane];
        }
        #pragma unroll
        for (int i = 0; i < 8; ++i) {
            float wa = __int_as_float(Ea[i].y), wb = __int_as_float(Eb[i].y);
            a0 = fmaf(wa, (float)((int)(signed char)(Ua[i] & 0xff)), a0);
            a1 = fmaf(wa, (float)((int)(signed char)(Ua[i] >> 8)), a1);
            c0 = fmaf(wb, (float)((int)(signed char)(Ub[i] & 0xff)), c0);
            c1 = fmaf(wb, (float)((int)(signed char)(Ub[i] >> 8)), c1);
        }
    }
    for (; ea < eA; ea += 8) {
        int2 E[8]; unsigned short U[8];
        #pragma unroll
        for (int i = 0; i < 8; ++i) E[i] = pedge[ea + i];
        #pragma unroll
        for (int i = 0; i < 8; ++i) U[i] = gq[(size_t)(E[i].x & 0xffff) * 64 + lane];
        #pragma unroll
        for (int i = 0; i < 8; ++i) {
            float w = __int_as_float(E[i].y);
            a0 = fmaf(w, (float)((int)(signed char)(U[i] & 0xff)), a0);
            a1 = fmaf(w, (float)((int)(signed char)(U[i] >> 8)), a1);
        }
    }
    for (; eb < eB; eb += 8) {
        int2 E[8]; unsigned short U[8];
        #pragma unroll
        for (int i = 0; i < 8; ++i) E[i] = pedge[eb + i];
        #pragma unroll
        for (int i = 0; i < 8; ++i) U[i] = gq[(size_t)(E[i].x & 0xffff) * 64 + lane];
        #pragma unroll
        for (int i = 0; i < 8; ++i) {
            float w = __int_as_float(E[i].y);
            c0 = fmaf(w, (float)((int)(signed char)(U[i] & 0xff)), c0);
            c1 = fmaf(w, (float)((int)(signed char)(U[i] >> 8)), c1);
        }
    }
    float mw = mixw[0];
    float mr = 1.f / (1.f + expf(-mw));
    int c = lane * 2;
    ushort2 mu0 = reinterpret_cast<const ushort2*>(mlp)[(size_t)d0 * 64 + lane];
    ushort2 mu1 = reinterpret_cast<const ushort2*>(mlp)[(size_t)d1 * 64 + lane];
    float g00 = a0 * IQS, g01 = a1 * IQS;
    float g10 = c0 * IQS, g11 = c1 * IQS;
    if (c < 64) {
        *reinterpret_cast<float2*>(out + (size_t)d0 * OD + c) =
            make_float2(g00 * mw + b2f(mu0.x) * (1.f - mw), g01 * mw + b2f(mu0.y) * (1.f - mw));
        *reinterpret_cast<float2*>(out + (size_t)d1 * OD + c) =
            make_float2(g10 * mw + b2f(mu1.x) * (1.f - mw), g11 * mw + b2f(mu1.y) * (1.f - mw));
    } else {
        float* ol = out + (size_t)NN * OD;
        *reinterpret_cast<float2*>(ol + (size_t)d0 * OD + (c - 64)) =
            make_float2(g00 * mr + b2f(mu0.x) * (1.f - mr), g01 * mr + b2f(mu0.y) * (1.f - mr));
        *reinterpret_cast<float2*>(ol + (size_t)d1 * OD + (c - 64)) =
            make_float2(g10 * mr + b2f(mu1.x) * (1.f - mr), g11 * mr + b2f(mu1.y) * (1.f - mr));
    }
}

// ---------------- host ----------------

extern "C" void kernel_launch(void* const* d_in, const int* in_sizes, int n_in,
                              void* d_out, int out_size, void* d_ws, size_t ws_size,
                              hipStream_t stream) {
    const float* input = (const float*)d_in[0];
    const int*   ei    = (const int*)d_in[1];
    const float* ew    = (const float*)d_in[2];
    const float* mixw  = (const float*)d_in[3];
    const float* hw    = (const float*)d_in[4];
    const float* hb    = (const float*)d_in[5];
    const float* mw_   = (const float*)d_in[6];
    const float* mb    = (const float*)d_in[7];
    const float* lw    = (const float*)d_in[8];
    const float* lb    = (const float*)d_in[9];
    float* out = (float*)d_out;

    const int* src = ei;
    const int* dst = ei + NE;

    char* ws = (char*)d_ws;
    size_t off = 0;
    auto alloc = [&](size_t bytes) -> void* {
        void* p = ws + off;
        off += (bytes + 255) & ~(size_t)255;
        return p;
    };
    int*   deg      = (int*)alloc((size_t)NN * 4);
    int*   offsets8 = (int*)alloc((size_t)(NN + 2) * 4);
    int*   chunkSum8= (int*)alloc((size_t)NCH * 4);
    int*   chunkOff8= (int*)alloc((size_t)(NCH + 1) * 4);
    int*   binSum   = (int*)alloc((size_t)NCH * 4);
    int*   binPrefix= (int*)alloc((size_t)(NCH + 1) * 4);
    int*   histT    = (int*)alloc((size_t)NHT * 4);
    int2*  bkt      = (int2*)alloc((size_t)NE * 8);
    int2*  pedge    = (int2*)alloc(((size_t)NE + 8 * NN) * 8);
    unsigned short* Wht  = (unsigned short*)alloc((size_t)256 * 256 * 2);
    unsigned short* Wmlt = (unsigned short*)alloc((size_t)128 * 256 * 2);
    unsigned short* support  = (unsigned short*)alloc((size_t)NN * KD * 2);  // bf16 (MLP path)
    signed char*    supq     = (signed char*)alloc((size_t)NN * KD);        // int8 (gather)
    signed char*    hgq      = (signed char*)alloc((size_t)NN * KD);        // int8 hidden (scale 16)
    signed char*    gcnq     = (signed char*)alloc((size_t)NN * 128);       // int8 (gather)
    unsigned short* mlp      = (unsigned short*)alloc((size_t)NN * 128 * 2); // bf16

    k_hist<<<NBLK, 256, 0, stream>>>(dst, histT);
    k_scanbins<<<NCH, 256, 0, stream>>>(histT, binSum);
    k_binscan<<<1, 256, 0, stream>>>(binSum, binPrefix);
    k_bucketw<<<NBLK, 256, 0, stream>>>(src, dst, ew, histT, binPrefix, bkt);
    k_deg2<<<NCH, 256, 0, stream>>>(bkt, binPrefix, deg, chunkSum8);
    k_scan_chunks<<<1, 256, 0, stream>>>(chunkSum8, chunkOff8);
    k_place2f<<<NCH, 256, 0, stream>>>(bkt, binPrefix, chunkOff8, deg, offsets8, pedge);

    k_convW<<<256, 256, 0, stream>>>(hw, mw_, lw, Wht, Wmlt);

    int mblk = (NN + 63) / 64;   // 782
    // GEMM1: support(bf16) + supq(int8) = bf16(input) @ hw   (N=256 -> y=2)
    k_gemm<0, 2><<<dim3(mblk, 2), 256, 0, stream>>>(input, Wht, hb, mb, lb, support, supq);
    // SpMM1 (int8 gather) + bias + relu -> hgq (int8, scale 16)
    k_spmm1<<<NN / 8, 256, 0, stream>>>(offsets8, pedge, (const unsigned*)supq, hb, (unsigned*)hgq);
    // GEMM2 (GCN): gcnq(int8) = dequant(hgq) @ [mw|lw]   (N=128 -> y=1)
    k_gemm<4, 3><<<dim3(mblk, 1), 256, 0, stream>>>(hgq, Wmlt, hb, mb, lb, gcnq, nullptr);
    // GEMM2 (MLP): mlp(bf16) = relu(support+hb) @ [mw|lw] + [mb|lb]
    k_gemm<2, 4><<<dim3(mblk, 1), 256, 0, stream>>>(support, Wmlt, hb, mb, lb, mlp, nullptr);
    // SpMM2 (int8 gather) + mixture combine with mlp -> d_out (write-once)
    k_spmm2<<<NN / 8, 256, 0, stream>>>(offsets8, pedge, (const unsigned short*)gcnq, mlp, mixw, out);
}

// Round 15
// 155.702 us; speedup vs baseline: 1.4602x; 1.0176x over previous
//
#include <hip/hip_runtime.h>
#include <math.h>

#define NN 50000
#define NE 800000
#define KD 256
#define OD 64
#define NCH ((NN + 255) / 256)   // 196 buckets/chunks of 256 nodes
#define EPB 4096                 // edges per histogram/bucket block
#define NBLK ((NE + EPB - 1) / EPB)   // 196 blocks
#define NHT (NCH * NBLK)         // histogram matrix entries (bin-major)

#define QS 32.0f      // int8 quant scale for support/gcn_pre
#define IQS (1.0f / 32.0f)
#define QS2 16.0f     // int8 quant scale for hidden (range +-7.94)
#define IQS2 (1.0f / 16.0f)

using bf16x8 = __attribute__((ext_vector_type(8))) short;
using f32x4  = __attribute__((ext_vector_type(4))) float;

__device__ __forceinline__ unsigned short f2b(float x) {
    union { float f; unsigned u; } c; c.f = x;
    unsigned r = (c.u + 0x7FFF + ((c.u >> 16) & 1)) >> 16;
    return (unsigned short)r;
}
__device__ __forceinline__ float b2f(unsigned short b) {
    union { unsigned u; float f; } c; c.u = ((unsigned)b) << 16;
    return c.f;
}
__device__ __forceinline__ signed char quant8(float v) {
    int q = __float2int_rn(v * QS);
    q = q > 127 ? 127 : (q < -127 ? -127 : q);
    return (signed char)q;
}
__device__ __forceinline__ unsigned quant16u(float v) {   // v >= 0 (post-relu), scale 16
    int q = __float2int_rn(v * QS2);
    return (unsigned)(q > 127 ? 127 : q);
}

// in-block inclusive scan helper over s[256]
__device__ __forceinline__ void blk_scan(int* s, int t) {
    for (int o = 1; o < 256; o <<= 1) {
        int x = (t >= o) ? s[t - o] : 0;
        __syncthreads();
        s[t] += x;
        __syncthreads();
    }
}

// ---------------- CSR build (counting-sort, padded-to-8, LDS-atomic only, 5 dispatches) ----

// dispatch 1: blocks [0,NBLK): per-block bucket histogram; blocks [NBLK, NBLK+256): weight convert
__global__ __launch_bounds__(256) void k_histconv(const int* __restrict__ dst,
                                                  int* __restrict__ histT,
                                                  const float* __restrict__ hw,
                                                  const float* __restrict__ mw_,
                                                  const float* __restrict__ lw,
                                                  unsigned short* __restrict__ Wht,
                                                  unsigned short* __restrict__ Wmlt) {
    __shared__ int bins[NCH];
    int t = threadIdx.x;
    if (blockIdx.x < NBLK) {
        int blk = blockIdx.x;
        if (t < NCH) bins[t] = 0;
        __syncthreads();
        int base = blk * EPB;
        #pragma unroll
        for (int i = 0; i < EPB / 256; ++i) {
            int e = base + i * 256 + t;
            if (e < NE) atomicAdd(&bins[dst[e] >> 8], 1);
        }
        __syncthreads();
        if (t < NCH) histT[t * NBLK + blk] = bins[t];   // bin-major
    } else {
        int idx = (blockIdx.x - NBLK) * 256 + t;
        if (idx < 256 * 256) {
            int n = idx >> 8, k = idx & 255;
            Wht[(size_t)n * 256 + k] = f2b(hw[(size_t)k * 256 + n]);
        }
        if (idx < 128 * 256) {
            int n = idx >> 8, k = idx & 255;
            float v = (n < 64) ? mw_[(size_t)k * 64 + n] : lw[(size_t)k * 64 + (n - 64)];
            Wmlt[(size_t)n * 256 + k] = f2b(v);
        }
    }
}

// dispatch 2: per-bin exclusive scan over its 196 block-counts + row total
__global__ __launch_bounds__(256) void k_scanbins(int* __restrict__ histT,
                                                  int* __restrict__ binSum) {
    __shared__ int s[256];
    int bin = blockIdx.x, t = threadIdx.x;
    int v = (t < NBLK) ? histT[bin * NBLK + t] : 0;
    s[t] = v;
    __syncthreads();
    blk_scan(s, t);
    if (t < NBLK) histT[bin * NBLK + t] = s[t] - v;
    if (t == NBLK - 1) binSum[bin] = s[t];
}

// dispatch 3: bucket-sorted scatter; bucket bases derived by in-block scan of binSum
__global__ __launch_bounds__(256) void k_bucketw(const int* __restrict__ src,
                                                 const int* __restrict__ dst,
                                                 const float* __restrict__ w,
                                                 const int* __restrict__ histT,
                                                 const int* __restrict__ binSum,
                                                 int2* __restrict__ bkt) {
    __shared__ int pre[256];
    __shared__ int cur[NCH];
    int t = threadIdx.x, blk = blockIdx.x;
    int v = (t < NCH) ? binSum[t] : 0;
    pre[t] = v;
    __syncthreads();
    blk_scan(pre, t);
    if (t < NCH) cur[t] = histT[t * NBLK + blk] + (pre[t] - v);   // excl prefix
    __syncthreads();
    int base = blk * EPB;
    #pragma unroll
    for (int i = 0; i < EPB / 256; ++i) {
        int e = base + i * 256 + t;
        if (e < NE) {
            int d = dst[e];
            int p = atomicAdd(&cur[d >> 8], 1);
            bkt[p] = make_int2((d << 16) | src[e], __float_as_int(w[e]));
        }
    }
}

// dispatch 4: per-bucket node degrees (LDS atomics, coalesced reads) + padded chunk sums
__global__ __launch_bounds__(256) void k_deg2(const int2* __restrict__ bkt,
                                              const int* __restrict__ binSum,
                                              int* __restrict__ deg,
                                              int* __restrict__ chunkSum8) {
    __shared__ int incl[256];
    __shared__ int cnt[256];
    int t = threadIdx.x, b = blockIdx.x;
    incl[t] = (t < NCH) ? binSum[t] : 0;
    cnt[t] = 0;
    __syncthreads();
    blk_scan(incl, t);
    int e0 = (b > 0) ? incl[b - 1] : 0;
    int e1 = incl[b];
    __syncthreads();
    for (int e = e0 + t; e < e1; e += 256)
        atomicAdd(&cnt[(((unsigned)bkt[e].x) >> 16) & 255], 1);
    __syncthreads();
    int node = b * 256 + t;
    int c = cnt[t];
    if (node < NN) deg[node] = c;
    __shared__ int s[256];
    s[t] = (node < NN) ? ((c + 7) & ~7) : 0;
    __syncthreads();
    for (int o = 128; o > 0; o >>= 1) {
        if (t < o) s[t] += s[t + o];
        __syncthreads();
    }
    if (t == 0) chunkSum8[b] = s[0];
}

// dispatch 5: fused offsets8 + place + pad-fill; chunk base + bucket range via in-block scans
__global__ __launch_bounds__(256) void k_place2f(const int2* __restrict__ bkt,
                                                 const int* __restrict__ binSum,
                                                 const int* __restrict__ chunkSum8,
                                                 const int* __restrict__ deg,
                                                 int* __restrict__ offsets8,
                                                 int2* __restrict__ pedge) {
    __shared__ int binc[256];
    __shared__ int cinc[256];
    __shared__ int s[256];
    __shared__ int ncur[256];
    int t = threadIdx.x, b = blockIdx.x;
    binc[t] = (t < NCH) ? binSum[t] : 0;
    __syncthreads();
    blk_scan(binc, t);
    cinc[t] = (t < NCH) ? chunkSum8[t] : 0;
    __syncthreads();
    blk_scan(cinc, t);
    int e0 = (b > 0) ? binc[b - 1] : 0;
    int e1 = binc[b];
    int chunkBase = (b > 0) ? cinc[b - 1] : 0;
    __syncthreads();
    int node = b * 256 + t;
    int dv = (node < NN) ? deg[node] : 0;
    int pv = (dv + 7) & ~7;
    s[t] = pv;
    __syncthreads();
    blk_scan(s, t);
    int excl = s[t] - pv + chunkBase;
    if (node <= NN) offsets8[node] = excl;
    ncur[t] = excl;
    __syncthreads();
    for (int e = e0 + t; e < e1; e += 256) {
        int2 v = bkt[e];
        int d = ((unsigned)v.x) >> 16;
        int p = atomicAdd(&ncur[d & 255], 1);
        pedge[p] = v;
    }
    __syncthreads();
    if (node < NN) {
        int p0 = ncur[t];          // = excl + dv
        int p1 = excl + pv;
        for (int p = p0; p < p1; ++p) pedge[p] = make_int2(0, 0);
    }
}

// ---------------- MFMA GEMM1: 64x128 tile, 4 waves, wave 32x64 ----------------
// A = f32 input (convert); epilogue: bf16 support (ld 256) + int8 supq (ld 256)

__global__ __launch_bounds__(256) void k_gemm1(const float* __restrict__ Ap,
                                               const unsigned short* __restrict__ Bt,
                                               unsigned short* __restrict__ supOut,
                                               signed char* __restrict__ supqOut) {
    __shared__ unsigned short As[64 * 64];
    __shared__ unsigned short Bs[128 * 64];
    const int tid = threadIdx.x;
    const int row0 = blockIdx.x * 64;
    const int n0 = blockIdx.y * 128;
    const int lane = tid & 63;
    const int w = tid >> 6, wm = w >> 1, wn = w & 1;
    const int lr = lane & 15, lg = lane >> 4;
    const int rA = tid >> 2, qA = tid & 3;
    const int rB = tid >> 1, hB = tid & 1;

    f32x4 acc[2][4] = {};

    for (int k0 = 0; k0 < KD; k0 += 64) {
        {
            int gr = row0 + rA;
            unsigned short tmp[16];
            if (gr < NN) {
                #pragma unroll
                for (int i = 0; i < 4; ++i) {
                    float4 v = *reinterpret_cast<const float4*>(
                        &Ap[(size_t)gr * KD + k0 + qA * 16 + i * 4]);
                    tmp[i * 4 + 0] = f2b(v.x); tmp[i * 4 + 1] = f2b(v.y);
                    tmp[i * 4 + 2] = f2b(v.z); tmp[i * 4 + 3] = f2b(v.w);
                }
            } else {
                #pragma unroll
                for (int i = 0; i < 16; ++i) tmp[i] = 0;
            }
            int s0 = (qA * 2) ^ (rA & 7);
            int s1 = (qA * 2 + 1) ^ (rA & 7);
            *reinterpret_cast<uint4*>(&As[rA * 64 + s0 * 8]) = *reinterpret_cast<const uint4*>(&tmp[0]);
            *reinterpret_cast<uint4*>(&As[rA * 64 + s1 * 8]) = *reinterpret_cast<const uint4*>(&tmp[8]);
        }
        {
            const unsigned short* B = Bt + (size_t)(n0 + rB) * KD + k0 + hB * 32;
            #pragma unroll
            for (int i = 0; i < 4; ++i) {
                uint4 u = *reinterpret_cast<const uint4*>(B + i * 8);
                int slot = (hB * 4 + i) ^ (rB & 7);
                *reinterpret_cast<uint4*>(&Bs[rB * 64 + slot * 8]) = u;
            }
        }
        __syncthreads();
        #pragma unroll
        for (int ks = 0; ks < 2; ++ks) {
            int slot = ks * 4 + lg;
            bf16x8 a[2], b[4];
            #pragma unroll
            for (int fm = 0; fm < 2; ++fm) {
                int ra = wm * 32 + fm * 16 + lr;
                a[fm] = *reinterpret_cast<const bf16x8*>(&As[ra * 64 + ((slot ^ (ra & 7))) * 8]);
            }
            #pragma unroll
            for (int fn = 0; fn < 4; ++fn) {
                int rb = wn * 64 + fn * 16 + lr;
                b[fn] = *reinterpret_cast<const bf16x8*>(&Bs[rb * 64 + ((slot ^ (rb & 7))) * 8]);
            }
            #pragma unroll
            for (int fm = 0; fm < 2; ++fm)
                #pragma unroll
                for (int fn = 0; fn < 4; ++fn)
                    acc[fm][fn] = __builtin_amdgcn_mfma_f32_16x16x32_bf16(a[fm], b[fn], acc[fm][fn], 0, 0, 0);
        }
        __syncthreads();
    }
    #pragma unroll
    for (int fm = 0; fm < 2; ++fm) {
        #pragma unroll
        for (int j = 0; j < 4; ++j) {
            int grow = row0 + wm * 32 + fm * 16 + lg * 4 + j;
            if (grow >= NN) continue;
            #pragma unroll
            for (int fn = 0; fn < 4; ++fn) {
                int gcol = n0 + wn * 64 + fn * 16 + lr;
                float v = acc[fm][fn][j];
                supOut[(size_t)grow * 256 + gcol] = f2b(v);
                supqOut[(size_t)grow * 256 + gcol] = quant8(v);
            }
        }
    }
}

// ---------------- merged GEMM2 (one dispatch): y=0 GCN (int8 A), y=1 MLP (bf16 A) ----------

__global__ __launch_bounds__(256) void k_gemm2(const signed char* __restrict__ hgq,
                                               const unsigned short* __restrict__ support,
                                               const unsigned short* __restrict__ Bt,
                                               const float* __restrict__ hbias,
                                               const float* __restrict__ mbias,
                                               const float* __restrict__ lbias,
                                               signed char* __restrict__ gcnq,
                                               unsigned short* __restrict__ mlpout) {
    __shared__ unsigned short As[64 * 64];
    __shared__ unsigned short Bs[128 * 64];
    const bool mlpMode = blockIdx.y != 0;
    const int tid = threadIdx.x;
    const int row0 = blockIdx.x * 64;
    const int lane = tid & 63;
    const int w = tid >> 6, wm = w >> 1, wn = w & 1;
    const int lr = lane & 15, lg = lane >> 4;
    const int rA = tid >> 2, qA = tid & 3;
    const int rB = tid >> 1, hB = tid & 1;

    f32x4 acc[2][4] = {};

    for (int k0 = 0; k0 < KD; k0 += 64) {
        {
            int gr = row0 + rA;
            unsigned short tmp[16];
            if (gr < NN) {
                if (mlpMode) {
                    *reinterpret_cast<uint4*>(&tmp[0]) =
                        *reinterpret_cast<const uint4*>(&support[(size_t)gr * KD + k0 + qA * 16]);
                    *reinterpret_cast<uint4*>(&tmp[8]) =
                        *reinterpret_cast<const uint4*>(&support[(size_t)gr * KD + k0 + qA * 16 + 8]);
                    #pragma unroll
                    for (int i = 0; i < 4; ++i) {
                        float4 hb4 = *reinterpret_cast<const float4*>(&hbias[k0 + qA * 16 + i * 4]);
                        tmp[i * 4 + 0] = f2b(fmaxf(b2f(tmp[i * 4 + 0]) + hb4.x, 0.f));
                        tmp[i * 4 + 1] = f2b(fmaxf(b2f(tmp[i * 4 + 1]) + hb4.y, 0.f));
                        tmp[i * 4 + 2] = f2b(fmaxf(b2f(tmp[i * 4 + 2]) + hb4.z, 0.f));
                        tmp[i * 4 + 3] = f2b(fmaxf(b2f(tmp[i * 4 + 3]) + hb4.w, 0.f));
                    }
                } else {
                    signed char q[16];
                    *reinterpret_cast<uint4*>(q) =
                        *reinterpret_cast<const uint4*>(&hgq[(size_t)gr * KD + k0 + qA * 16]);
                    #pragma unroll
                    for (int i = 0; i < 16; ++i) tmp[i] = f2b((float)q[i] * IQS2);
                }
            } else {
                #pragma unroll
                for (int i = 0; i < 16; ++i) tmp[i] = 0;
            }
            int s0 = (qA * 2) ^ (rA & 7);
            int s1 = (qA * 2 + 1) ^ (rA & 7);
            *reinterpret_cast<uint4*>(&As[rA * 64 + s0 * 8]) = *reinterpret_cast<const uint4*>(&tmp[0]);
            *reinterpret_cast<uint4*>(&As[rA * 64 + s1 * 8]) = *reinterpret_cast<const uint4*>(&tmp[8]);
        }
        {
            const unsigned short* B = Bt + (size_t)rB * KD + k0 + hB * 32;
            #pragma unroll
            for (int i = 0; i < 4; ++i) {
                uint4 u = *reinterpret_cast<const uint4*>(B + i * 8);
                int slot = (hB * 4 + i) ^ (rB & 7);
                *reinterpret_cast<uint4*>(&Bs[rB * 64 + slot * 8]) = u;
            }
        }
        __syncthreads();
        #pragma unroll
        for (int ks = 0; ks < 2; ++ks) {
            int slot = ks * 4 + lg;
            bf16x8 a[2], b[4];
            #pragma unroll
            for (int fm = 0; fm < 2; ++fm) {
                int ra = wm * 32 + fm * 16 + lr;
                a[fm] = *reinterpret_cast<const bf16x8*>(&As[ra * 64 + ((slot ^ (ra & 7))) * 8]);
            }
            #pragma unroll
            for (int fn = 0; fn < 4; ++fn) {
                int rb = wn * 64 + fn * 16 + lr;
                b[fn] = *reinterpret_cast<const bf16x8*>(&Bs[rb * 64 + ((slot ^ (rb & 7))) * 8]);
            }
            #pragma unroll
            for (int fm = 0; fm < 2; ++fm)
                #pragma unroll
                for (int fn = 0; fn < 4; ++fn)
                    acc[fm][fn] = __builtin_amdgcn_mfma_f32_16x16x32_bf16(a[fm], b[fn], acc[fm][fn], 0, 0, 0);
        }
        __syncthreads();
    }
    #pragma unroll
    for (int fm = 0; fm < 2; ++fm) {
        #pragma unroll
        for (int j = 0; j < 4; ++j) {
            int grow = row0 + wm * 32 + fm * 16 + lg * 4 + j;
            if (grow >= NN) continue;
            #pragma unroll
            for (int fn = 0; fn < 4; ++fn) {
                int gcol = wn * 64 + fn * 16 + lr;
                float v = acc[fm][fn][j];
                if (mlpMode) {
                    float b = (gcol < 64) ? mbias[gcol] : lbias[gcol - 64];
                    mlpout[(size_t)grow * 128 + gcol] = f2b(v + b);
                } else {
                    gcnq[(size_t)grow * 128 + gcol] = quant8(v);
                }
            }
        }
    }
}

// ---------------- SpMM1 (int8 gather) + bias + relu -> hgq int8 (scale 16), 2 dsts/wave ----

__global__ __launch_bounds__(256) void k_spmm1(const int* __restrict__ off8,
                                               const int2* __restrict__ pedge,
                                               const unsigned* __restrict__ supq,
                                               const float* __restrict__ bias,
                                               unsigned* __restrict__ hgq) {
    int lane = threadIdx.x & 63;
    int wid = blockIdx.x * 4 + (threadIdx.x >> 6);
    int d0 = wid * 2, d1 = d0 + 1;
    int ea = off8[d0], eA = off8[d0 + 1], eB = off8[d0 + 2];
    int eb = eA;
    float a0 = 0.f, a1 = 0.f, a2 = 0.f, a3 = 0.f;
    float c0 = 0.f, c1 = 0.f, c2 = 0.f, c3 = 0.f;
    for (; ea < eA && eb < eB; ea += 8, eb += 8) {
        int2 Ea[8], Eb[8];
        unsigned Ua[8], Ub[8];
        #pragma unroll
        for (int i = 0; i < 8; ++i) { Ea[i] = pedge[ea + i]; Eb[i] = pedge[eb + i]; }
        #pragma unroll
        for (int i = 0; i < 8; ++i) {
            Ua[i] = supq[(size_t)(Ea[i].x & 0xffff) * 64 + lane];
            Ub[i] = supq[(size_t)(Eb[i].x & 0xffff) * 64 + lane];
        }
        #pragma unroll
        for (int i = 0; i < 8; ++i) {
            float wa = __int_as_float(Ea[i].y), wb = __int_as_float(Eb[i].y);
            unsigned ua = Ua[i], ub = Ub[i];
            a0 = fmaf(wa, (float)((int)(signed char)(ua)), a0);
            a1 = fmaf(wa, (float)((int)(signed char)(ua >> 8)), a1);
            a2 = fmaf(wa, (float)((int)(signed char)(ua >> 16)), a2);
            a3 = fmaf(wa, (float)((int)(signed char)(ua >> 24)), a3);
            c0 = fmaf(wb, (float)((int)(signed char)(ub)), c0);
            c1 = fmaf(wb, (float)((int)(signed char)(ub >> 8)), c1);
            c2 = fmaf(wb, (float)((int)(signed char)(ub >> 16)), c2);
            c3 = fmaf(wb, (float)((int)(signed char)(ub >> 24)), c3);
        }
    }
    for (; ea < eA; ea += 8) {
        int2 E[8]; unsigned U[8];
        #pragma unroll
        for (int i = 0; i < 8; ++i) E[i] = pedge[ea + i];
        #pragma unroll
        for (int i = 0; i < 8; ++i) U[i] = supq[(size_t)(E[i].x & 0xffff) * 64 + lane];
        #pragma unroll
        for (int i = 0; i < 8; ++i) {
            float w = __int_as_float(E[i].y); unsigned u = U[i];
            a0 = fmaf(w, (float)((int)(signed char)(u)), a0);
            a1 = fmaf(w, (float)((int)(signed char)(u >> 8)), a1);
            a2 = fmaf(w, (float)((int)(signed char)(u >> 16)), a2);
            a3 = fmaf(w, (float)((int)(signed char)(u >> 24)), a3);
        }
    }
    for (; eb < eB; eb += 8) {
        int2 E[8]; unsigned U[8];
        #pragma unroll
        for (int i = 0; i < 8; ++i) E[i] = pedge[eb + i];
        #pragma unroll
        for (int i = 0; i < 8; ++i) U[i] = supq[(size_t)(E[i].x & 0xffff) * 64 + lane];
        #pragma unroll
        for (int i = 0; i < 8; ++i) {
            float w = __int_as_float(E[i].y); unsigned u = U[i];
            c0 = fmaf(w, (float)((int)(signed char)(u)), c0);
            c1 = fmaf(w, (float)((int)(signed char)(u >> 8)), c1);
            c2 = fmaf(w, (float)((int)(signed char)(u >> 16)), c2);
            c3 = fmaf(w, (float)((int)(signed char)(u >> 24)), c3);
        }
    }
    float4 b = *reinterpret_cast<const float4*>(&bias[lane * 4]);
    unsigned oa = quant16u(fmaxf(a0 * IQS + b.x, 0.f))
                | (quant16u(fmaxf(a1 * IQS + b.y, 0.f)) << 8)
                | (quant16u(fmaxf(a2 * IQS + b.z, 0.f)) << 16)
                | (quant16u(fmaxf(a3 * IQS + b.w, 0.f)) << 24);
    unsigned oc = quant16u(fmaxf(c0 * IQS + b.x, 0.f))
                | (quant16u(fmaxf(c1 * IQS + b.y, 0.f)) << 8)
                | (quant16u(fmaxf(c2 * IQS + b.z, 0.f)) << 16)
                | (quant16u(fmaxf(c3 * IQS + b.w, 0.f)) << 24);
    hgq[(size_t)d0 * 64 + lane] = oa;
    hgq[(size_t)d1 * 64 + lane] = oc;
}

// ---------------- SpMM2 (int8 gather, 128 dims) + mixture with mlp, 2 dsts/wave ------------

__global__ __launch_bounds__(256) void k_spmm2(const int* __restrict__ off8,
                                               const int2* __restrict__ pedge,
                                               const unsigned short* __restrict__ gq,
                                               const unsigned short* __restrict__ mlp,
                                               const float* __restrict__ mixw,
                                               float* __restrict__ out) {
    int lane = threadIdx.x & 63;
    int wid = blockIdx.x * 4 + (threadIdx.x >> 6);
    int d0 = wid * 2, d1 = d0 + 1;
    int ea = off8[d0], eA = off8[d0 + 1], eB = off8[d0 + 2];
    int eb = eA;
    float a0 = 0.f, a1 = 0.f, c0 = 0.f, c1 = 0.f;
    for (; ea < eA && eb < eB; ea += 8, eb += 8) {
        int2 Ea[8], Eb[8];
        unsigned short Ua[8], Ub[8];
        #pragma unroll
        for (int i = 0; i < 8; ++i) { Ea[i] = pedge[ea + i]; Eb[i] = pedge[eb + i]; }
        #pragma unroll
        for (int i = 0; i < 8; ++i) {
            Ua[i] = gq[(size_t)(Ea[i].x & 0xffff) * 64 + lane];
            Ub[i] = gq[(size_t)(Eb[i].x & 0xffff) * 64 + lane];
        }
        #pragma unroll
        for (int i = 0; i < 8; ++i) {
            float wa = __int_as_float(Ea[i].y), wb = __int_as_float(Eb[i].y);
            a0 = fmaf(wa, (float)((int)(signed char)(Ua[i] & 0xff)), a0);
            a1 = fmaf(wa, (float)((int)(signed char)(Ua[i] >> 8)), a1);
            c0 = fmaf(wb, (float)((int)(signed char)(Ub[i] & 0xff)), c0);
            c1 = fmaf(wb, (float)((int)(signed char)(Ub[i] >> 8)), c1);
        }
    }
    for (; ea < eA; ea += 8) {
        int2 E[8]; unsigned short U[8];
        #pragma unroll
        for (int i = 0; i < 8; ++i) E[i] = pedge[ea + i];
        #pragma unroll
        for (int i = 0; i < 8; ++i) U[i] = gq[(size_t)(E[i].x & 0xffff) * 64 + lane];
        #pragma unroll
        for (int i = 0; i < 8; ++i) {
            float w = __int_as_float(E[i].y);
            a0 = fmaf(w, (float)((int)(signed char)(U[i] & 0xff)), a0);
            a1 = fmaf(w, (float)((int)(signed char)(U[i] >> 8)), a1);
        }
    }
    for (; eb < eB; eb += 8) {
        int2 E[8]; unsigned short U[8];
        #pragma unroll
        for (int i = 0; i < 8; ++i) E[i] = pedge[eb + i];
        #pragma unroll
        for (int i = 0; i < 8; ++i) U[i] = gq[(size_t)(E[i].x & 0xffff) * 64 + lane];
        #pragma unroll
        for (int i = 0; i < 8; ++i) {
            float w = __int_as_float(E[i].y);
            c0 = fmaf(w, (float)((int)(signed char)(U[i] & 0xff)), c0);
            c1 = fmaf(w, (float)((int)(signed char)(U[i] >> 8)), c1);
        }
    }
    float mw = mixw[0];
    float mr = 1.f / (1.f + expf(-mw));
    int c = lane * 2;
    ushort2 mu0 = reinterpret_cast<const ushort2*>(mlp)[(size_t)d0 * 64 + lane];
    ushort2 mu1 = reinterpret_cast<const ushort2*>(mlp)[(size_t)d1 * 64 + lane];
    float g00 = a0 * IQS, g01 = a1 * IQS;
    float g10 = c0 * IQS, g11 = c1 * IQS;
    if (c < 64) {
        *reinterpret_cast<float2*>(out + (size_t)d0 * OD + c) =
            make_float2(g00 * mw + b2f(mu0.x) * (1.f - mw), g01 * mw + b2f(mu0.y) * (1.f - mw));
        *reinterpret_cast<float2*>(out + (size_t)d1 * OD + c) =
            make_float2(g10 * mw + b2f(mu1.x) * (1.f - mw), g11 * mw + b2f(mu1.y) * (1.f - mw));
    } else {
        float* ol = out + (size_t)NN * OD;
        *reinterpret_cast<float2*>(ol + (size_t)d0 * OD + (c - 64)) =
            make_float2(g00 * mr + b2f(mu0.x) * (1.f - mr), g01 * mr + b2f(mu0.y) * (1.f - mr));
        *reinterpret_cast<float2*>(ol + (size_t)d1 * OD + (c - 64)) =
            make_float2(g10 * mr + b2f(mu1.x) * (1.f - mr), g11 * mr + b2f(mu1.y) * (1.f - mr));
    }
}

// ---------------- host ----------------

extern "C" void kernel_launch(void* const* d_in, const int* in_sizes, int n_in,
                              void* d_out, int out_size, void* d_ws, size_t ws_size,
                              hipStream_t stream) {
    const float* input = (const float*)d_in[0];
    const int*   ei    = (const int*)d_in[1];
    const float* ew    = (const float*)d_in[2];
    const float* mixw  = (const float*)d_in[3];
    const float* hw    = (const float*)d_in[4];
    const float* hb    = (const float*)d_in[5];
    const float* mw_   = (const float*)d_in[6];
    const float* mb    = (const float*)d_in[7];
    const float* lw    = (const float*)d_in[8];
    const float* lb    = (const float*)d_in[9];
    float* out = (float*)d_out;

    const int* src = ei;
    const int* dst = ei + NE;

    char* ws = (char*)d_ws;
    size_t off = 0;
    auto alloc = [&](size_t bytes) -> void* {
        void* p = ws + off;
        off += (bytes + 255) & ~(size_t)255;
        return p;
    };
    int*   deg      = (int*)alloc((size_t)NN * 4);
    int*   offsets8 = (int*)alloc((size_t)(NN + 2) * 4);
    int*   chunkSum8= (int*)alloc((size_t)NCH * 4);
    int*   binSum   = (int*)alloc((size_t)NCH * 4);
    int*   histT    = (int*)alloc((size_t)NHT * 4);
    int2*  bkt      = (int2*)alloc((size_t)NE * 8);
    int2*  pedge    = (int2*)alloc(((size_t)NE + 8 * NN) * 8);
    unsigned short* Wht  = (unsigned short*)alloc((size_t)256 * 256 * 2);
    unsigned short* Wmlt = (unsigned short*)alloc((size_t)128 * 256 * 2);
    unsigned short* support  = (unsigned short*)alloc((size_t)NN * KD * 2);
    signed char*    supq     = (signed char*)alloc((size_t)NN * KD);
    signed char*    hgq      = (signed char*)alloc((size_t)NN * KD);
    signed char*    gcnq     = (signed char*)alloc((size_t)NN * 128);
    unsigned short* mlp      = (unsigned short*)alloc((size_t)NN * 128 * 2);

    // CSR build + weight convert: 5 dispatches
    k_histconv<<<NBLK + 256, 256, 0, stream>>>(dst, histT, hw, mw_, lw, Wht, Wmlt);
    k_scanbins<<<NCH, 256, 0, stream>>>(histT, binSum);
    k_bucketw<<<NBLK, 256, 0, stream>>>(src, dst, ew, histT, binSum, bkt);
    k_deg2<<<NCH, 256, 0, stream>>>(bkt, binSum, deg, chunkSum8);
    k_place2f<<<NCH, 256, 0, stream>>>(bkt, binSum, chunkSum8, deg, offsets8, pedge);

    int mblk = (NN + 63) / 64;   // 782
    // GEMM1: support(bf16) + supq(int8) = bf16(input) @ hw
    k_gemm1<<<dim3(mblk, 2), 256, 0, stream>>>(input, Wht, support, supq);
    // SpMM1 (int8 gather) + bias + relu -> hgq (int8, scale 16)
    k_spmm1<<<NN / 8, 256, 0, stream>>>(offsets8, pedge, (const unsigned*)supq, hb, (unsigned*)hgq);
    // merged GEMM2: y=0 GCN (gcnq int8), y=1 MLP (mlp bf16)
    k_gemm2<<<dim3(mblk, 2), 256, 0, stream>>>(hgq, support, Wmlt, hb, mb, lb, gcnq, mlp);
    // SpMM2 (int8 gather) + mixture combine with mlp -> d_out (write-once)
    k_spmm2<<<NN / 8, 256, 0, stream>>>(offsets8, pedge, (const unsigned short*)gcnq, mlp, mixw, out);
}

// Round 16
// 150.561 us; speedup vs baseline: 1.5101x; 1.0341x over previous
//
#include <hip/hip_runtime.h>
#include <math.h>

#define NN 50000
#define NE 800000
#define KD 256
#define OD 64
#define NCH ((NN + 255) / 256)   // 196 buckets/chunks of 256 nodes
#define EPB 4096                 // edges per histogram/bucket block
#define NBLK ((NE + EPB - 1) / EPB)   // 196 blocks
#define NHT (NCH * NBLK)         // histogram matrix entries (bin-major)

#define QS 32.0f      // int8 quant scale for support/gcn_pre
#define IQS (1.0f / 32.0f)
#define QS2 16.0f     // int8 quant scale for hidden (range +-7.94)
#define IQS2 (1.0f / 16.0f)

using bf16x8 = __attribute__((ext_vector_type(8))) short;
using f32x4  = __attribute__((ext_vector_type(4))) float;

__device__ __forceinline__ unsigned short f2b(float x) {
    union { float f; unsigned u; } c; c.f = x;
    unsigned r = (c.u + 0x7FFF + ((c.u >> 16) & 1)) >> 16;
    return (unsigned short)r;
}
__device__ __forceinline__ float b2f(unsigned short b) {
    union { unsigned u; float f; } c; c.u = ((unsigned)b) << 16;
    return c.f;
}
__device__ __forceinline__ signed char quant8(float v) {
    int q = __float2int_rn(v * QS);
    q = q > 127 ? 127 : (q < -127 ? -127 : q);
    return (signed char)q;
}
__device__ __forceinline__ unsigned quant16u(float v) {   // v >= 0 (post-relu), scale 16
    int q = __float2int_rn(v * QS2);
    return (unsigned)(q > 127 ? 127 : q);
}

// in-block inclusive scan helper over s[256]
__device__ __forceinline__ void blk_scan(int* s, int t) {
    for (int o = 1; o < 256; o <<= 1) {
        int x = (t >= o) ? s[t - o] : 0;
        __syncthreads();
        s[t] += x;
        __syncthreads();
    }
}

// ---------------- CSR build (counting-sort, padded-to-8, LDS-atomic only) ----------------

// dispatch 1: blocks [0,NBLK): bucket histogram; blocks [NBLK, NBLK+256): weight convert
__global__ __launch_bounds__(256) void k_histconv(const int* __restrict__ dst,
                                                  int* __restrict__ histT,
                                                  const float* __restrict__ hw,
                                                  const float* __restrict__ mw_,
                                                  const float* __restrict__ lw,
                                                  unsigned short* __restrict__ Wht,
                                                  unsigned short* __restrict__ Wmlt) {
    __shared__ int bins[NCH];
    int t = threadIdx.x;
    if (blockIdx.x < NBLK) {
        int blk = blockIdx.x;
        if (t < NCH) bins[t] = 0;
        __syncthreads();
        int base = blk * EPB;
        #pragma unroll
        for (int i = 0; i < EPB / 256; ++i) {
            int e = base + i * 256 + t;
            if (e < NE) atomicAdd(&bins[dst[e] >> 8], 1);
        }
        __syncthreads();
        if (t < NCH) histT[t * NBLK + blk] = bins[t];   // bin-major
    } else {
        int idx = (blockIdx.x - NBLK) * 256 + t;
        if (idx < 256 * 256) {
            int n = idx >> 8, k = idx & 255;
            Wht[(size_t)n * 256 + k] = f2b(hw[(size_t)k * 256 + n]);
        }
        if (idx < 128 * 256) {
            int n = idx >> 8, k = idx & 255;
            float v = (n < 64) ? mw_[(size_t)k * 64 + n] : lw[(size_t)k * 64 + (n - 64)];
            Wmlt[(size_t)n * 256 + k] = f2b(v);
        }
    }
}

// dispatch 2: per-bin exclusive scan over its 196 block-counts + row total
__global__ __launch_bounds__(256) void k_scanbins(int* __restrict__ histT,
                                                  int* __restrict__ binSum) {
    __shared__ int s[256];
    int bin = blockIdx.x, t = threadIdx.x;
    int v = (t < NBLK) ? histT[bin * NBLK + t] : 0;
    s[t] = v;
    __syncthreads();
    blk_scan(s, t);
    if (t < NBLK) histT[bin * NBLK + t] = s[t] - v;
    if (t == NBLK - 1) binSum[bin] = s[t];
}

// dispatch 3: bucket-sorted scatter; bucket bases via in-block scan of binSum
__global__ __launch_bounds__(256) void k_bucketw(const int* __restrict__ src,
                                                 const int* __restrict__ dst,
                                                 const float* __restrict__ w,
                                                 const int* __restrict__ histT,
                                                 const int* __restrict__ binSum,
                                                 int2* __restrict__ bkt) {
    __shared__ int pre[256];
    __shared__ int cur[NCH];
    int t = threadIdx.x, blk = blockIdx.x;
    int v = (t < NCH) ? binSum[t] : 0;
    pre[t] = v;
    __syncthreads();
    blk_scan(pre, t);
    if (t < NCH) cur[t] = histT[t * NBLK + blk] + (pre[t] - v);
    __syncthreads();
    int base = blk * EPB;
    #pragma unroll
    for (int i = 0; i < EPB / 256; ++i) {
        int e = base + i * 256 + t;
        if (e < NE) {
            int d = dst[e];
            int p = atomicAdd(&cur[d >> 8], 1);
            bkt[p] = make_int2((d << 16) | src[e], __float_as_int(w[e]));
        }
    }
}

// dispatch 4: per-bucket node degrees + padded chunk sums
__global__ __launch_bounds__(256) void k_deg2(const int2* __restrict__ bkt,
                                              const int* __restrict__ binSum,
                                              int* __restrict__ deg,
                                              int* __restrict__ chunkSum8) {
    __shared__ int incl[256];
    __shared__ int cnt[256];
    int t = threadIdx.x, b = blockIdx.x;
    incl[t] = (t < NCH) ? binSum[t] : 0;
    cnt[t] = 0;
    __syncthreads();
    blk_scan(incl, t);
    int e0 = (b > 0) ? incl[b - 1] : 0;
    int e1 = incl[b];
    __syncthreads();
    for (int e = e0 + t; e < e1; e += 256)
        atomicAdd(&cnt[(((unsigned)bkt[e].x) >> 16) & 255], 1);
    __syncthreads();
    int node = b * 256 + t;
    int c = cnt[t];
    if (node < NN) deg[node] = c;
    __shared__ int s[256];
    s[t] = (node < NN) ? ((c + 7) & ~7) : 0;
    __syncthreads();
    for (int o = 128; o > 0; o >>= 1) {
        if (t < o) s[t] += s[t + o];
        __syncthreads();
    }
    if (t == 0) chunkSum8[b] = s[0];
}

// dispatch 5: fused offsets8 + place + pad-fill
__global__ __launch_bounds__(256) void k_place2f(const int2* __restrict__ bkt,
                                                 const int* __restrict__ binSum,
                                                 const int* __restrict__ chunkSum8,
                                                 const int* __restrict__ deg,
                                                 int* __restrict__ offsets8,
                                                 int2* __restrict__ pedge) {
    __shared__ int binc[256];
    __shared__ int cinc[256];
    __shared__ int s[256];
    __shared__ int ncur[256];
    int t = threadIdx.x, b = blockIdx.x;
    binc[t] = (t < NCH) ? binSum[t] : 0;
    __syncthreads();
    blk_scan(binc, t);
    cinc[t] = (t < NCH) ? chunkSum8[t] : 0;
    __syncthreads();
    blk_scan(cinc, t);
    int e0 = (b > 0) ? binc[b - 1] : 0;
    int e1 = binc[b];
    int chunkBase = (b > 0) ? cinc[b - 1] : 0;
    __syncthreads();
    int node = b * 256 + t;
    int dv = (node < NN) ? deg[node] : 0;
    int pv = (dv + 7) & ~7;
    s[t] = pv;
    __syncthreads();
    blk_scan(s, t);
    int excl = s[t] - pv + chunkBase;
    if (node <= NN) offsets8[node] = excl;
    ncur[t] = excl;
    __syncthreads();
    for (int e = e0 + t; e < e1; e += 256) {
        int2 v = bkt[e];
        int d = ((unsigned)v.x) >> 16;
        int p = atomicAdd(&ncur[d & 255], 1);
        pedge[p] = v;
    }
    __syncthreads();
    if (node < NN) {
        int p0 = ncur[t];          // = excl + dv
        int p1 = excl + pv;
        for (int p = p0; p < p1; ++p) pedge[p] = make_int2(0, 0);
    }
}

// ---------------- MFMA GEMM1: 64x128 tile, 4 waves, wave 32x64; int8-only output ----------

__global__ __launch_bounds__(256) void k_gemm1(const float* __restrict__ Ap,
                                               const unsigned short* __restrict__ Bt,
                                               signed char* __restrict__ supqOut) {
    __shared__ unsigned short As[64 * 64];
    __shared__ unsigned short Bs[128 * 64];
    const int tid = threadIdx.x;
    const int row0 = blockIdx.x * 64;
    const int n0 = blockIdx.y * 128;
    const int lane = tid & 63;
    const int w = tid >> 6, wm = w >> 1, wn = w & 1;
    const int lr = lane & 15, lg = lane >> 4;
    const int rA = tid >> 2, qA = tid & 3;
    const int rB = tid >> 1, hB = tid & 1;

    f32x4 acc[2][4] = {};

    for (int k0 = 0; k0 < KD; k0 += 64) {
        {
            int gr = row0 + rA;
            unsigned short tmp[16];
            if (gr < NN) {
                #pragma unroll
                for (int i = 0; i < 4; ++i) {
                    float4 v = *reinterpret_cast<const float4*>(
                        &Ap[(size_t)gr * KD + k0 + qA * 16 + i * 4]);
                    tmp[i * 4 + 0] = f2b(v.x); tmp[i * 4 + 1] = f2b(v.y);
                    tmp[i * 4 + 2] = f2b(v.z); tmp[i * 4 + 3] = f2b(v.w);
                }
            } else {
                #pragma unroll
                for (int i = 0; i < 16; ++i) tmp[i] = 0;
            }
            int s0 = (qA * 2) ^ (rA & 7);
            int s1 = (qA * 2 + 1) ^ (rA & 7);
            *reinterpret_cast<uint4*>(&As[rA * 64 + s0 * 8]) = *reinterpret_cast<const uint4*>(&tmp[0]);
            *reinterpret_cast<uint4*>(&As[rA * 64 + s1 * 8]) = *reinterpret_cast<const uint4*>(&tmp[8]);
        }
        {
            const unsigned short* B = Bt + (size_t)(n0 + rB) * KD + k0 + hB * 32;
            #pragma unroll
            for (int i = 0; i < 4; ++i) {
                uint4 u = *reinterpret_cast<const uint4*>(B + i * 8);
                int slot = (hB * 4 + i) ^ (rB & 7);
                *reinterpret_cast<uint4*>(&Bs[rB * 64 + slot * 8]) = u;
            }
        }
        __syncthreads();
        #pragma unroll
        for (int ks = 0; ks < 2; ++ks) {
            int slot = ks * 4 + lg;
            bf16x8 a[2], b[4];
            #pragma unroll
            for (int fm = 0; fm < 2; ++fm) {
                int ra = wm * 32 + fm * 16 + lr;
                a[fm] = *reinterpret_cast<const bf16x8*>(&As[ra * 64 + ((slot ^ (ra & 7))) * 8]);
            }
            #pragma unroll
            for (int fn = 0; fn < 4; ++fn) {
                int rb = wn * 64 + fn * 16 + lr;
                b[fn] = *reinterpret_cast<const bf16x8*>(&Bs[rb * 64 + ((slot ^ (rb & 7))) * 8]);
            }
            #pragma unroll
            for (int fm = 0; fm < 2; ++fm)
                #pragma unroll
                for (int fn = 0; fn < 4; ++fn)
                    acc[fm][fn] = __builtin_amdgcn_mfma_f32_16x16x32_bf16(a[fm], b[fn], acc[fm][fn], 0, 0, 0);
        }
        __syncthreads();
    }
    #pragma unroll
    for (int fm = 0; fm < 2; ++fm) {
        #pragma unroll
        for (int j = 0; j < 4; ++j) {
            int grow = row0 + wm * 32 + fm * 16 + lg * 4 + j;
            if (grow >= NN) continue;
            #pragma unroll
            for (int fn = 0; fn < 4; ++fn) {
                int gcol = n0 + wn * 64 + fn * 16 + lr;
                supqOut[(size_t)grow * 256 + gcol] = quant8(acc[fm][fn][j]);
            }
        }
    }
}

// ---------------- merged GEMM2: y=0 GCN (hgq int8, x1/16), y=1 MLP (supq int8, x1/32+bias+relu)

__global__ __launch_bounds__(256) void k_gemm2(const signed char* __restrict__ hgq,
                                               const signed char* __restrict__ supq,
                                               const unsigned short* __restrict__ Bt,
                                               const float* __restrict__ hbias,
                                               const float* __restrict__ mbias,
                                               const float* __restrict__ lbias,
                                               signed char* __restrict__ gcnq,
                                               unsigned short* __restrict__ mlpout) {
    __shared__ unsigned short As[64 * 64];
    __shared__ unsigned short Bs[128 * 64];
    const bool mlpMode = blockIdx.y != 0;
    const int tid = threadIdx.x;
    const int row0 = blockIdx.x * 64;
    const int lane = tid & 63;
    const int w = tid >> 6, wm = w >> 1, wn = w & 1;
    const int lr = lane & 15, lg = lane >> 4;
    const int rA = tid >> 2, qA = tid & 3;
    const int rB = tid >> 1, hB = tid & 1;

    f32x4 acc[2][4] = {};

    for (int k0 = 0; k0 < KD; k0 += 64) {
        {
            int gr = row0 + rA;
            unsigned short tmp[16];
            if (gr < NN) {
                signed char q[16];
                const signed char* Aq = mlpMode ? supq : hgq;
                *reinterpret_cast<uint4*>(q) =
                    *reinterpret_cast<const uint4*>(&Aq[(size_t)gr * KD + k0 + qA * 16]);
                if (mlpMode) {
                    #pragma unroll
                    for (int i = 0; i < 4; ++i) {
                        float4 hb4 = *reinterpret_cast<const float4*>(&hbias[k0 + qA * 16 + i * 4]);
                        tmp[i * 4 + 0] = f2b(fmaxf((float)q[i * 4 + 0] * IQS + hb4.x, 0.f));
                        tmp[i * 4 + 1] = f2b(fmaxf((float)q[i * 4 + 1] * IQS + hb4.y, 0.f));
                        tmp[i * 4 + 2] = f2b(fmaxf((float)q[i * 4 + 2] * IQS + hb4.z, 0.f));
                        tmp[i * 4 + 3] = f2b(fmaxf((float)q[i * 4 + 3] * IQS + hb4.w, 0.f));
                    }
                } else {
                    #pragma unroll
                    for (int i = 0; i < 16; ++i) tmp[i] = f2b((float)q[i] * IQS2);
                }
            } else {
                #pragma unroll
                for (int i = 0; i < 16; ++i) tmp[i] = 0;
            }
            int s0 = (qA * 2) ^ (rA & 7);
            int s1 = (qA * 2 + 1) ^ (rA & 7);
            *reinterpret_cast<uint4*>(&As[rA * 64 + s0 * 8]) = *reinterpret_cast<const uint4*>(&tmp[0]);
            *reinterpret_cast<uint4*>(&As[rA * 64 + s1 * 8]) = *reinterpret_cast<const uint4*>(&tmp[8]);
        }
        {
            const unsigned short* B = Bt + (size_t)rB * KD + k0 + hB * 32;
            #pragma unroll
            for (int i = 0; i < 4; ++i) {
                uint4 u = *reinterpret_cast<const uint4*>(B + i * 8);
                int slot = (hB * 4 + i) ^ (rB & 7);
                *reinterpret_cast<uint4*>(&Bs[rB * 64 + slot * 8]) = u;
            }
        }
        __syncthreads();
        #pragma unroll
        for (int ks = 0; ks < 2; ++ks) {
            int slot = ks * 4 + lg;
            bf16x8 a[2], b[4];
            #pragma unroll
            for (int fm = 0; fm < 2; ++fm) {
                int ra = wm * 32 + fm * 16 + lr;
                a[fm] = *reinterpret_cast<const bf16x8*>(&As[ra * 64 + ((slot ^ (ra & 7))) * 8]);
            }
            #pragma unroll
            for (int fn = 0; fn < 4; ++fn) {
                int rb = wn * 64 + fn * 16 + lr;
                b[fn] = *reinterpret_cast<const bf16x8*>(&Bs[rb * 64 + ((slot ^ (rb & 7))) * 8]);
            }
            #pragma unroll
            for (int fm = 0; fm < 2; ++fm)
                #pragma unroll
                for (int fn = 0; fn < 4; ++fn)
                    acc[fm][fn] = __builtin_amdgcn_mfma_f32_16x16x32_bf16(a[fm], b[fn], acc[fm][fn], 0, 0, 0);
        }
        __syncthreads();
    }
    #pragma unroll
    for (int fm = 0; fm < 2; ++fm) {
        #pragma unroll
        for (int j = 0; j < 4; ++j) {
            int grow = row0 + wm * 32 + fm * 16 + lg * 4 + j;
            if (grow >= NN) continue;
            #pragma unroll
            for (int fn = 0; fn < 4; ++fn) {
                int gcol = wn * 64 + fn * 16 + lr;
                float v = acc[fm][fn][j];
                if (mlpMode) {
                    float b = (gcol < 64) ? mbias[gcol] : lbias[gcol - 64];
                    mlpout[(size_t)grow * 128 + gcol] = f2b(v + b);
                } else {
                    gcnq[(size_t)grow * 128 + gcol] = quant8(v);
                }
            }
        }
    }
}

// ---------------- SpMM1 (int8 gather) + bias + relu -> hgq int8 (scale 16), 2 dsts/wave ----

__global__ __launch_bounds__(256) void k_spmm1(const int* __restrict__ off8,
                                               const int2* __restrict__ pedge,
                                               const unsigned* __restrict__ supq,
                                               const float* __restrict__ bias,
                                               unsigned* __restrict__ hgq) {
    int lane = threadIdx.x & 63;
    int wid = blockIdx.x * 4 + (threadIdx.x >> 6);
    int d0 = wid * 2, d1 = d0 + 1;
    int ea = off8[d0], eA = off8[d0 + 1], eB = off8[d0 + 2];
    int eb = eA;
    float a0 = 0.f, a1 = 0.f, a2 = 0.f, a3 = 0.f;
    float c0 = 0.f, c1 = 0.f, c2 = 0.f, c3 = 0.f;
    for (; ea < eA && eb < eB; ea += 8, eb += 8) {
        int2 Ea[8], Eb[8];
        unsigned Ua[8], Ub[8];
        #pragma unroll
        for (int i = 0; i < 8; ++i) { Ea[i] = pedge[ea + i]; Eb[i] = pedge[eb + i]; }
        #pragma unroll
        for (int i = 0; i < 8; ++i) {
            Ua[i] = supq[(size_t)(Ea[i].x & 0xffff) * 64 + lane];
            Ub[i] = supq[(size_t)(Eb[i].x & 0xffff) * 64 + lane];
        }
        #pragma unroll
        for (int i = 0; i < 8; ++i) {
            float wa = __int_as_float(Ea[i].y), wb = __int_as_float(Eb[i].y);
            unsigned ua = Ua[i], ub = Ub[i];
            a0 = fmaf(wa, (float)((int)(signed char)(ua)), a0);
            a1 = fmaf(wa, (float)((int)(signed char)(ua >> 8)), a1);
            a2 = fmaf(wa, (float)((int)(signed char)(ua >> 16)), a2);
            a3 = fmaf(wa, (float)((int)(signed char)(ua >> 24)), a3);
            c0 = fmaf(wb, (float)((int)(signed char)(ub)), c0);
            c1 = fmaf(wb, (float)((int)(signed char)(ub >> 8)), c1);
            c2 = fmaf(wb, (float)((int)(signed char)(ub >> 16)), c2);
            c3 = fmaf(wb, (float)((int)(signed char)(ub >> 24)), c3);
        }
    }
    for (; ea < eA; ea += 8) {
        int2 E[8]; unsigned U[8];
        #pragma unroll
        for (int i = 0; i < 8; ++i) E[i] = pedge[ea + i];
        #pragma unroll
        for (int i = 0; i < 8; ++i) U[i] = supq[(size_t)(E[i].x & 0xffff) * 64 + lane];
        #pragma unroll
        for (int i = 0; i < 8; ++i) {
            float w = __int_as_float(E[i].y); unsigned u = U[i];
            a0 = fmaf(w, (float)((int)(signed char)(u)), a0);
            a1 = fmaf(w, (float)((int)(signed char)(u >> 8)), a1);
            a2 = fmaf(w, (float)((int)(signed char)(u >> 16)), a2);
            a3 = fmaf(w, (float)((int)(signed char)(u >> 24)), a3);
        }
    }
    for (; eb < eB; eb += 8) {
        int2 E[8]; unsigned U[8];
        #pragma unroll
        for (int i = 0; i < 8; ++i) E[i] = pedge[eb + i];
        #pragma unroll
        for (int i = 0; i < 8; ++i) U[i] = supq[(size_t)(E[i].x & 0xffff) * 64 + lane];
        #pragma unroll
        for (int i = 0; i < 8; ++i) {
            float w = __int_as_float(E[i].y); unsigned u = U[i];
            c0 = fmaf(w, (float)((int)(signed char)(u)), c0);
            c1 = fmaf(w, (float)((int)(signed char)(u >> 8)), c1);
            c2 = fmaf(w, (float)((int)(signed char)(u >> 16)), c2);
            c3 = fmaf(w, (float)((int)(signed char)(u >> 24)), c3);
        }
    }
    float4 b = *reinterpret_cast<const float4*>(&bias[lane * 4]);
    unsigned oa = quant16u(fmaxf(a0 * IQS + b.x, 0.f))
                | (quant16u(fmaxf(a1 * IQS + b.y, 0.f)) << 8)
                | (quant16u(fmaxf(a2 * IQS + b.z, 0.f)) << 16)
                | (quant16u(fmaxf(a3 * IQS + b.w, 0.f)) << 24);
    unsigned oc = quant16u(fmaxf(c0 * IQS + b.x, 0.f))
                | (quant16u(fmaxf(c1 * IQS + b.y, 0.f)) << 8)
                | (quant16u(fmaxf(c2 * IQS + b.z, 0.f)) << 16)
                | (quant16u(fmaxf(c3 * IQS + b.w, 0.f)) << 24);
    hgq[(size_t)d0 * 64 + lane] = oa;
    hgq[(size_t)d1 * 64 + lane] = oc;
}

// ---------------- SpMM2 (int8 gather, 128 dims) + mixture with mlp, 2 dsts/wave ------------

__global__ __launch_bounds__(256) void k_spmm2(const int* __restrict__ off8,
                                               const int2* __restrict__ pedge,
                                               const unsigned short* __restrict__ gq,
                                               const unsigned short* __restrict__ mlp,
                                               const float* __restrict__ mixw,
                                               float* __restrict__ out) {
    int lane = threadIdx.x & 63;
    int wid = blockIdx.x * 4 + (threadIdx.x >> 6);
    int d0 = wid * 2, d1 = d0 + 1;
    int ea = off8[d0], eA = off8[d0 + 1], eB = off8[d0 + 2];
    int eb = eA;
    float a0 = 0.f, a1 = 0.f, c0 = 0.f, c1 = 0.f;
    for (; ea < eA && eb < eB; ea += 8, eb += 8) {
        int2 Ea[8], Eb[8];
        unsigned short Ua[8], Ub[8];
        #pragma unroll
        for (int i = 0; i < 8; ++i) { Ea[i] = pedge[ea + i]; Eb[i] = pedge[eb + i]; }
        #pragma unroll
        for (int i = 0; i < 8; ++i) {
            Ua[i] = gq[(size_t)(Ea[i].x & 0xffff) * 64 + lane];
            Ub[i] = gq[(size_t)(Eb[i].x & 0xffff) * 64 + lane];
        }
        #pragma unroll
        for (int i = 0; i < 8; ++i) {
            float wa = __int_as_float(Ea[i].y), wb = __int_as_float(Eb[i].y);
            a0 = fmaf(wa, (float)((int)(signed char)(Ua[i] & 0xff)), a0);
            a1 = fmaf(wa, (float)((int)(signed char)(Ua[i] >> 8)), a1);
            c0 = fmaf(wb, (float)((int)(signed char)(Ub[i] & 0xff)), c0);
            c1 = fmaf(wb, (float)((int)(signed char)(Ub[i] >> 8)), c1);
        }
    }
    for (; ea < eA; ea += 8) {
        int2 E[8]; unsigned short U[8];
        #pragma unroll
        for (int i = 0; i < 8; ++i) E[i] = pedge[ea + i];
        #pragma unroll
        for (int i = 0; i < 8; ++i) U[i] = gq[(size_t)(E[i].x & 0xffff) * 64 + lane];
        #pragma unroll
        for (int i = 0; i < 8; ++i) {
            float w = __int_as_float(E[i].y);
            a0 = fmaf(w, (float)((int)(signed char)(U[i] & 0xff)), a0);
            a1 = fmaf(w, (float)((int)(signed char)(U[i] >> 8)), a1);
        }
    }
    for (; eb < eB; eb += 8) {
        int2 E[8]; unsigned short U[8];
        #pragma unroll
        for (int i = 0; i < 8; ++i) E[i] = pedge[eb + i];
        #pragma unroll
        for (int i = 0; i < 8; ++i) U[i] = gq[(size_t)(E[i].x & 0xffff) * 64 + lane];
        #pragma unroll
        for (int i = 0; i < 8; ++i) {
            float w = __int_as_float(E[i].y);
            c0 = fmaf(w, (float)((int)(signed char)(U[i] & 0xff)), c0);
            c1 = fmaf(w, (float)((int)(signed char)(U[i] >> 8)), c1);
        }
    }
    float mw = mixw[0];
    float mr = 1.f / (1.f + expf(-mw));
    int c = lane * 2;
    ushort2 mu0 = reinterpret_cast<const ushort2*>(mlp)[(size_t)d0 * 64 + lane];
    ushort2 mu1 = reinterpret_cast<const ushort2*>(mlp)[(size_t)d1 * 64 + lane];
    float g00 = a0 * IQS, g01 = a1 * IQS;
    float g10 = c0 * IQS, g11 = c1 * IQS;
    if (c < 64) {
        *reinterpret_cast<float2*>(out + (size_t)d0 * OD + c) =
            make_float2(g00 * mw + b2f(mu0.x) * (1.f - mw), g01 * mw + b2f(mu0.y) * (1.f - mw));
        *reinterpret_cast<float2*>(out + (size_t)d1 * OD + c) =
            make_float2(g10 * mw + b2f(mu1.x) * (1.f - mw), g11 * mw + b2f(mu1.y) * (1.f - mw));
    } else {
        float* ol = out + (size_t)NN * OD;
        *reinterpret_cast<float2*>(ol + (size_t)d0 * OD + (c - 64)) =
            make_float2(g00 * mr + b2f(mu0.x) * (1.f - mr), g01 * mr + b2f(mu0.y) * (1.f - mr));
        *reinterpret_cast<float2*>(ol + (size_t)d1 * OD + (c - 64)) =
            make_float2(g10 * mr + b2f(mu1.x) * (1.f - mr), g11 * mr + b2f(mu1.y) * (1.f - mr));
    }
}

// ---------------- host ----------------

extern "C" void kernel_launch(void* const* d_in, const int* in_sizes, int n_in,
                              void* d_out, int out_size, void* d_ws, size_t ws_size,
                              hipStream_t stream) {
    const float* input = (const float*)d_in[0];
    const int*   ei    = (const int*)d_in[1];
    const float* ew    = (const float*)d_in[2];
    const float* mixw  = (const float*)d_in[3];
    const float* hw    = (const float*)d_in[4];
    const float* hb    = (const float*)d_in[5];
    const float* mw_   = (const float*)d_in[6];
    const float* mb    = (const float*)d_in[7];
    const float* lw    = (const float*)d_in[8];
    const float* lb    = (const float*)d_in[9];
    float* out = (float*)d_out;

    const int* src = ei;
    const int* dst = ei + NE;

    char* ws = (char*)d_ws;
    size_t off = 0;
    auto alloc = [&](size_t bytes) -> void* {
        void* p = ws + off;
        off += (bytes + 255) & ~(size_t)255;
        return p;
    };
    int*   deg      = (int*)alloc((size_t)NN * 4);
    int*   offsets8 = (int*)alloc((size_t)(NN + 2) * 4);
    int*   chunkSum8= (int*)alloc((size_t)NCH * 4);
    int*   binSum   = (int*)alloc((size_t)NCH * 4);
    int*   histT    = (int*)alloc((size_t)NHT * 4);
    int2*  bkt      = (int2*)alloc((size_t)NE * 8);
    int2*  pedge    = (int2*)alloc(((size_t)NE + 8 * NN) * 8);
    unsigned short* Wht  = (unsigned short*)alloc((size_t)256 * 256 * 2);
    unsigned short* Wmlt = (unsigned short*)alloc((size_t)128 * 256 * 2);
    signed char*    supq     = (signed char*)alloc((size_t)NN * KD);       // int8 support
    signed char*    hgq      = (signed char*)alloc((size_t)NN * KD);       // int8 hidden
    signed char*    gcnq     = (signed char*)alloc((size_t)NN * 128);      // int8 gcn_pre
    unsigned short* mlp      = (unsigned short*)alloc((size_t)NN * 128 * 2);

    // CSR build + weight convert: 5 dispatches
    k_histconv<<<NBLK + 256, 256, 0, stream>>>(dst, histT, hw, mw_, lw, Wht, Wmlt);
    k_scanbins<<<NCH, 256, 0, stream>>>(histT, binSum);
    k_bucketw<<<NBLK, 256, 0, stream>>>(src, dst, ew, histT, binSum, bkt);
    k_deg2<<<NCH, 256, 0, stream>>>(bkt, binSum, deg, chunkSum8);
    k_place2f<<<NCH, 256, 0, stream>>>(bkt, binSum, chunkSum8, deg, offsets8, pedge);

    int mblk = (NN + 63) / 64;   // 782
    // GEMM1: supq(int8) = bf16(input) @ hw
    k_gemm1<<<dim3(mblk, 2), 256, 0, stream>>>(input, Wht, supq);
    // SpMM1 (int8 gather) + bias + relu -> hgq (int8, scale 16)
    k_spmm1<<<NN / 8, 256, 0, stream>>>(offsets8, pedge, (const unsigned*)supq, hb, (unsigned*)hgq);
    // merged GEMM2: y=0 GCN (hgq -> gcnq), y=1 MLP (supq -> mlp)
    k_gemm2<<<dim3(mblk, 2), 256, 0, stream>>>(hgq, supq, Wmlt, hb, mb, lb, gcnq, mlp);
    // SpMM2 (int8 gather) + mixture combine with mlp -> d_out (write-once)
    k_spmm2<<<NN / 8, 256, 0, stream>>>(offsets8, pedge, (const unsigned short*)gcnq, mlp, mixw, out);
}